// Round 2
// baseline (632.399 us; speedup 1.0000x reference)
//
#include <hip/hip_runtime.h>

// Pipeline: k_zero -> k_score(+hist) -> k_select -> k_compact -> k_sort
//           -> k_ioumat -> k_greedy -> k_loss -> k_final

static constexpr int NB   = 8;
static constexpr int NA   = 25200;
static constexpr int NCLS = 80;
static constexpr int CH   = 85;
static constexpr int NT   = 16;    // 8 clean + 8 patch tasks
static constexpr int KMAX = 1024;
static constexpr int NBIN = 65536; // 16-bit prefix histogram
static constexpr int CAP  = 4096;  // candidate buffer per task

// workspace byte offsets (all 16B aligned)
static constexpr size_t OFF_KEYS = 0;                                   // 1,612,800
static constexpr size_t OFF_CLS  = OFF_KEYS + (size_t)NT * NA * 4;      // 1,612,800
static constexpr size_t OFF_BOX  = OFF_CLS  + (size_t)NT * NA * 4;      // 262,144
static constexpr size_t OFF_CLSK = OFF_BOX  + (size_t)NT * KMAX * 16;   // 65,536
static constexpr size_t OFF_VALK = OFF_CLSK + (size_t)NT * KMAX * 4;    // 65,536
static constexpr size_t OFF_KEEP = OFF_VALK + (size_t)NT * KMAX * 4;    // 2,048
static constexpr size_t OFF_SUP  = OFF_KEEP + (size_t)NT * 16 * 8;      // 2,097,152
static constexpr size_t OFF_PART = OFF_SUP  + (size_t)NT * KMAX * 16 * 8; // 512
static constexpr size_t OFF_HIST = OFF_PART + 512;                      // NT*NBIN*4 = 4,194,304
static constexpr size_t OFF_CNT  = OFF_HIST + (size_t)NT * NBIN * 4;    // NT*2*4 = 128
static constexpr size_t OFF_THR  = OFF_CNT  + 128;                      // NT*2*4 = 128
static constexpr size_t OFF_CAND = OFF_THR  + 128;                      // NT*CAP*8 = 524,288
// total ~10.5 MB

__device__ __forceinline__ unsigned okey(float f) {
  unsigned u = __float_as_uint(f);
  return (u & 0x80000000u) ? ~u : (u | 0x80000000u);
}

// ---------------- K0: zero hist + counters ----------------
__global__ __launch_bounds__(256) void k_zero(unsigned* __restrict__ hist,
                                              unsigned* __restrict__ cnt) {
  const int n = NT * NBIN;
  for (int i = blockIdx.x * 256 + threadIdx.x; i < n; i += gridDim.x * 256) hist[i] = 0;
  if (blockIdx.x == 0 && threadIdx.x < NT * 2) cnt[threadIdx.x] = 0;
}

// ---------------- K1: per-anchor score/class + histogram ----------------
__global__ __launch_bounds__(256) void k_score(const float* __restrict__ clean,
                                               const float* __restrict__ patch,
                                               unsigned* __restrict__ keys,
                                               int* __restrict__ clsArr,
                                               unsigned* __restrict__ hist) {
#pragma clang fp contract(off)
  const int t  = blockIdx.y;
  const int a0 = blockIdx.x * 128;
  const int nA = (NA - a0 < 128) ? (NA - a0) : 128;
  const float conf_th = (t < 8) ? 0.25f : 0.001f;
  const float* __restrict__ src = ((t < 8) ? clean : patch) + (size_t)(t & 7) * NA * CH;
  __shared__ float rows[128 * CH];
  const float4* g4 = (const float4*)(src + (size_t)a0 * CH);
  float4* s4 = (float4*)rows;
  const int n4 = (nA * CH) >> 2;
  for (int i = threadIdx.x; i < n4; i += 256) s4[i] = g4[i];
  __syncthreads();
  if (threadIdx.x < nA) {
    const float* r = rows + threadIdx.x * CH;
    const float obj = r[4];
    float best = r[5] * obj;   // products first (matches ref argmax over cls_conf)
    int bc = 0;
    for (int c = 1; c < NCLS; ++c) {
      float v = r[5 + c] * obj;
      if (v > best) { best = v; bc = c; }
    }
    const bool valid = (obj > conf_th) && (best > conf_th);
    const float score = valid ? best : -1e30f;
    const int a = a0 + threadIdx.x;
    const unsigned key = okey(score);
    keys[(size_t)t * NA + a]   = key;
    clsArr[(size_t)t * NA + a] = bc;
    atomicAdd(&hist[(size_t)t * NBIN + (key >> 16)], 1u);
  }
}

// ---------------- K2: exact threshold bin via hierarchical suffix scan ----------------
__global__ __launch_bounds__(256) void k_select(const unsigned* __restrict__ hist,
                                                unsigned* __restrict__ thr) {
  const int t = blockIdx.x;
  const unsigned K = (t < 8) ? 512u : 1024u;
  const unsigned* h = hist + (size_t)t * NBIN;
  __shared__ unsigned s[256];
  __shared__ int s_chunk;
  __shared__ unsigned s_accAbove;
  const int tid = threadIdx.x;
  // chunk sums (256 bins each)
  {
    const uint4* h4 = (const uint4*)(h + tid * 256);
    unsigned sum = 0;
    for (int i = 0; i < 64; ++i) { uint4 v = h4[i]; sum += v.x + v.y + v.z + v.w; }
    s[tid] = sum;
  }
  __syncthreads();
  // inclusive suffix scan over chunks: s[t] = sum_{t'>=t} s[t']
  for (int off = 1; off < 256; off <<= 1) {
    unsigned v = s[tid];
    if (tid + off < 256) v += s[tid + off];
    __syncthreads();
    s[tid] = v;
    __syncthreads();
  }
  // chunk containing the K-th largest
  {
    bool pred = s[tid] >= K;
    bool next = (tid == 255) ? false : (s[tid + 1] >= K);
    if (pred && !next) {
      s_chunk = tid;
      s_accAbove = (tid == 255) ? 0u : s[tid + 1];
    }
  }
  __syncthreads();
  const int c = s_chunk;
  const unsigned accAbove = s_accAbove;
  // fine suffix scan within chunk c
  s[tid] = h[c * 256 + tid];
  __syncthreads();
  for (int off = 1; off < 256; off <<= 1) {
    unsigned v = s[tid];
    if (tid + off < 256) v += s[tid + off];
    __syncthreads();
    s[tid] = v;
    __syncthreads();
  }
  {
    bool pred = accAbove + s[tid] >= K;
    bool next = (tid == 255) ? false : (accAbove + s[tid + 1] >= K);
    if (pred && !next) {
      thr[t] = (unsigned)(c * 256 + tid);  // threshold 16-bit bin B
    }
  }
}

// ---------------- K3: compact candidates ----------------
__global__ __launch_bounds__(256) void k_compact(const unsigned* __restrict__ keys,
                                                 const unsigned* __restrict__ thr,
                                                 unsigned* __restrict__ cnt,
                                                 unsigned long long* __restrict__ cand) {
  const int t = blockIdx.y;
  const int a = blockIdx.x * 256 + threadIdx.x;
  if (a >= NA) return;
  const unsigned B = thr[t];
  const unsigned key = keys[(size_t)t * NA + a];
  const unsigned p = key >> 16;
  if (p < B) return;
  const unsigned long long item =
      ((unsigned long long)key << 32) | (unsigned)(~(unsigned)a);
  if (p > B) {
    unsigned pos = atomicAdd(&cnt[t * 2 + 0], 1u);
    if (pos < 1024u) cand[(size_t)t * CAP + pos] = item;          // hi region [0,1024)
  } else {
    unsigned pos = atomicAdd(&cnt[t * 2 + 1], 1u);
    if (pos < (unsigned)(CAP - 1024)) cand[(size_t)t * CAP + 1024 + pos] = item; // eq region
  }
}

// ---------------- K4: bitonic sort candidates + gather top-K ----------------
__global__ __launch_bounds__(512) void k_sort(const float* __restrict__ clean,
                                              const float* __restrict__ patch,
                                              const unsigned* __restrict__ cnt,
                                              const unsigned long long* __restrict__ cand,
                                              const int* __restrict__ clsArr,
                                              float* __restrict__ boxesK,
                                              int* __restrict__ clsK,
                                              int* __restrict__ validK) {
#pragma clang fp contract(off)
  const int t = blockIdx.x;
  const int K = (t < 8) ? 512 : 1024;
  const float conf_th = (t < 8) ? 0.25f : 0.001f;
  __shared__ unsigned long long buf[CAP];
  const unsigned nHi = min(cnt[t * 2 + 0], 1024u);
  const unsigned nEq = min(cnt[t * 2 + 1], (unsigned)(CAP - 1024));
  const unsigned long long* cd = cand + (size_t)t * CAP;
  for (int i = threadIdx.x; i < CAP; i += 512) {
    unsigned long long v = 0ull;
    if (i < 1024) { if ((unsigned)i < nHi) v = cd[i]; }
    else          { if ((unsigned)(i - 1024) < nEq) v = cd[i]; }
    buf[i] = v;
  }
  __syncthreads();
  // bitonic sort descending; equal keys -> larger ~idx (= smaller idx) first
  for (int kk2 = 2; kk2 <= CAP; kk2 <<= 1) {
    for (int j = kk2 >> 1; j > 0; j >>= 1) {
      for (int i = threadIdx.x; i < CAP; i += 512) {
        int ixj = i ^ j;
        if (ixj > i) {
          unsigned long long a = buf[i], b = buf[ixj];
          bool desc = ((i & kk2) == 0);
          if (desc ? (a < b) : (a > b)) { buf[i] = b; buf[ixj] = a; }
        }
      }
      __syncthreads();
    }
  }
  const float* __restrict__ src = ((t < 8) ? clean : patch) + (size_t)(t & 7) * NA * CH;
  const unsigned vkey = okey(conf_th);
  for (int k = threadIdx.x; k < K; k += 512) {
    unsigned long long v = buf[k];
    unsigned key = (unsigned)(v >> 32);
    int idx = (int)(~(unsigned)(v & 0xFFFFFFFFull));
    const float* r = src + (size_t)idx * CH;
    float cx = r[0], cy = r[1], w = r[2], h = r[3];
    float hw = w * 0.5f, hh = h * 0.5f;
    float* bo = boxesK + ((size_t)t * KMAX + k) * 4;
    bo[0] = cx - hw; bo[1] = cy - hh; bo[2] = cx + hw; bo[3] = cy + hh;
    clsK[t * KMAX + k]   = clsArr[(size_t)t * NA + idx];
    validK[t * KMAX + k] = (key > vkey) ? 1 : 0;
  }
}

// ---------------- K5: suppression bit-matrix ----------------
__global__ __launch_bounds__(256) void k_ioumat(const float* __restrict__ boxesK,
                                                const int* __restrict__ clsK,
                                                unsigned long long* __restrict__ sup) {
#pragma clang fp contract(off)
  const int t  = blockIdx.y;
  const int K  = (t < 8) ? 512 : 1024;
  const int lw = (t < 8) ? 3 : 4;
  const int nw = 1 << lw;
  __shared__ float X1[KMAX], Y1[KMAX], X2[KMAX], Y2[KMAX], AR[KMAX];
  for (int i = threadIdx.x; i < K; i += 256) {
    const float* bo = boxesK + ((size_t)t * KMAX + i) * 4;
    float off = (float)clsK[t * KMAX + i] * 4096.0f;
    float x1 = bo[0] + off, y1 = bo[1] + off, x2 = bo[2] + off, y2 = bo[3] + off;
    X1[i] = x1; Y1[i] = y1; X2[i] = x2; Y2[i] = y2;
    AR[i] = (x2 - x1) * (y2 - y1);
  }
  __syncthreads();
  const int total = K * nw;
  unsigned long long* supt = sup + (size_t)t * (KMAX * 16);
  for (int widx = blockIdx.x * 256 + threadIdx.x; widx < total; widx += 16 * 256) {
    int i  = widx >> lw;
    int wc = widx & (nw - 1);
    float x1i = X1[i], y1i = Y1[i], x2i = X2[i], y2i = Y2[i], ai = AR[i];
    unsigned long long m = 0ull;
    int jbase = wc << 6;
    for (int l = 0; l < 64; ++l) {
      int j = jbase + l;
      if (j > i) {
        float tlx = fmaxf(x1i, X1[j]);
        float tly = fmaxf(y1i, Y1[j]);
        float brx = fminf(x2i, X2[j]);
        float bry = fminf(y2i, Y2[j]);
        float w = fmaxf(brx - tlx, 0.0f);
        float h = fmaxf(bry - tly, 0.0f);
        float inter = w * h;
        float uni = (ai + AR[j]) - inter;
        uni = (uni > 0.0f) ? uni : 1.0f;
        float iou = inter / uni;
        if (iou > 0.45f) m |= (1ull << l);
      }
    }
    supt[(size_t)i * nw + wc] = m;
  }
}

// ---------------- K6: greedy NMS, word-blocked (single wave / task) ----------------
__global__ __launch_bounds__(64) void k_greedy(const unsigned long long* __restrict__ sup,
                                               const int* __restrict__ validK,
                                               unsigned long long* __restrict__ keepw) {
  const int t  = blockIdx.x;
  const int K  = (t < 8) ? 512 : 1024;
  const int nw = K >> 6;
  const int lane = threadIdx.x;
  __shared__ unsigned long long buf[KMAX];
  const unsigned long long* base = sup + (size_t)t * (KMAX * 16);
  unsigned long long remv = 0ull;
  for (int W = 0; W < nw; ++W) {
    const uint4* g4 = (const uint4*)(base + (size_t)W * 64 * nw);
    uint4* b4 = (uint4*)buf;
    const int nq = nw >> 1;
    uint4 tmp[8];
#pragma unroll
    for (int q = 0; q < 8; ++q) if (q < nq) tmp[q] = g4[q * 64 + lane];
#pragma unroll
    for (int q = 0; q < 8; ++q) if (q < nq) b4[q * 64 + lane] = tmp[q];
    __syncthreads();
    int v = validK[t * KMAX + W * 64 + lane];
    unsigned long long cur = __ballot(v != 0);
    cur &= ~__shfl(remv, W);
#pragma unroll
    for (int r = 0; r < 64; ++r) {
      unsigned long long msk = 0ull - ((cur >> r) & 1ull);
      cur &= ~(buf[r * nw + W] & msk);
    }
    if (lane > W && lane < nw) {
      for (int r = 0; r < 64; ++r) {
        if ((cur >> r) & 1ull) remv |= buf[r * nw + lane];
      }
    }
    if (lane == 0) keepw[t * 16 + W] = cur;
    __syncthreads();
  }
}

// ---------------- K7: masked-max IoU loss partials ----------------
__global__ __launch_bounds__(256) void k_loss(const float* __restrict__ boxesK,
                                              const int* __restrict__ clsK,
                                              const unsigned long long* __restrict__ keepw,
                                              float* __restrict__ part) {
#pragma clang fp contract(off)
  const int img = blockIdx.y;
  const int chunk = blockIdx.x;
  const int tp = 8 + img;
  __shared__ float px1[KMAX], py1[KMAX], px2[KMAX], py2[KMAX], pa[KMAX];
  __shared__ int pcls[KMAX];
  __shared__ float red[256];
  for (int j = threadIdx.x; j < KMAX; j += 256) {
    const float* bo = boxesK + ((size_t)tp * KMAX + j) * 4;
    float x1 = bo[0] / 640.0f, y1 = bo[1] / 640.0f;
    float x2 = bo[2] / 640.0f, y2 = bo[3] / 640.0f;
    px1[j] = x1; py1[j] = y1; px2[j] = x2; py2[j] = y2;
    pa[j] = (x2 - x1) * (y2 - y1);
    int kept = (int)((keepw[tp * 16 + (j >> 6)] >> (j & 63)) & 1ull);
    pcls[j] = kept ? clsK[tp * KMAX + j] : -1;
  }
  __syncthreads();
  const int row = chunk * 64 + (threadIdx.x & 63);
  const int stripe = threadIdx.x >> 6;
  const int ck = (int)((keepw[img * 16 + (row >> 6)] >> (row & 63)) & 1ull);
  const float* bo = boxesK + ((size_t)img * KMAX + row) * 4;
  float cx1 = bo[0] / 640.0f, cy1 = bo[1] / 640.0f;
  float cx2 = bo[2] / 640.0f, cy2 = bo[3] / 640.0f;
  float ca = (cx2 - cx1) * (cy2 - cy1);
  const int ccls = clsK[img * KMAX + row];
  float m = 0.0f;
  if (ck) {
    const int j0 = stripe * 256;
    for (int j = j0; j < j0 + 256; ++j) {
      if (pcls[j] == ccls) {
        float tlx = fmaxf(cx1, px1[j]);
        float tly = fmaxf(cy1, py1[j]);
        float brx = fminf(cx2, px2[j]);
        float bry = fminf(cy2, py2[j]);
        float w = fmaxf(brx - tlx, 0.0f);
        float h = fmaxf(bry - tly, 0.0f);
        float inter = w * h;
        float uni = (ca + pa[j]) - inter;
        uni = (uni > 0.0f) ? uni : 1.0f;
        m = fmaxf(m, inter / uni);
      }
    }
  }
  red[threadIdx.x] = m;
  __syncthreads();
  if (threadIdx.x < 64) {
    float mm = fmaxf(fmaxf(red[threadIdx.x], red[threadIdx.x + 64]),
                     fmaxf(red[threadIdx.x + 128], red[threadIdx.x + 192]));
    float sv = ck ? mm : 0.0f;
    float nv = ck ? 1.0f : 0.0f;
    for (int off = 32; off > 0; off >>= 1) {
      sv += __shfl_down(sv, off);
      nv += __shfl_down(nv, off);
    }
    if (threadIdx.x == 0) {
      int b = img * 8 + chunk;
      part[b * 2 + 0] = sv;
      part[b * 2 + 1] = nv;
    }
  }
}

// ---------------- K8: deterministic final reduce ----------------
__global__ __launch_bounds__(64) void k_final(const float* __restrict__ part,
                                              float* __restrict__ out) {
  int lane = threadIdx.x;
  float sv = part[lane * 2 + 0];
  float nv = part[lane * 2 + 1];
  for (int off = 32; off > 0; off >>= 1) {
    sv += __shfl_down(sv, off);
    nv += __shfl_down(nv, off);
  }
  if (lane == 0) out[0] = (nv > 0.0f) ? (1.0f - sv / fmaxf(nv, 1.0f)) : 1.0f;
}

extern "C" void kernel_launch(void* const* d_in, const int* in_sizes, int n_in,
                              void* d_out, int out_size, void* d_ws, size_t ws_size,
                              hipStream_t stream) {
  const float* clean = (const float*)d_in[0];
  const float* patch = (const float*)d_in[1];
  char* ws = (char*)d_ws;
  unsigned* keys            = (unsigned*)(ws + OFF_KEYS);
  int* clsArr               = (int*)(ws + OFF_CLS);
  float* boxesK             = (float*)(ws + OFF_BOX);
  int* clsK                 = (int*)(ws + OFF_CLSK);
  int* validK               = (int*)(ws + OFF_VALK);
  unsigned long long* keepw = (unsigned long long*)(ws + OFF_KEEP);
  unsigned long long* sup   = (unsigned long long*)(ws + OFF_SUP);
  float* part               = (float*)(ws + OFF_PART);
  unsigned* hist            = (unsigned*)(ws + OFF_HIST);
  unsigned* cnt             = (unsigned*)(ws + OFF_CNT);
  unsigned* thr             = (unsigned*)(ws + OFF_THR);
  unsigned long long* cand  = (unsigned long long*)(ws + OFF_CAND);
  float* out                = (float*)d_out;

  k_zero   <<<1024, 256, 0, stream>>>(hist, cnt);
  k_score  <<<dim3((NA + 127) / 128, NT), 256, 0, stream>>>(clean, patch, keys, clsArr, hist);
  k_select <<<NT, 256, 0, stream>>>(hist, thr);
  k_compact<<<dim3((NA + 255) / 256, NT), 256, 0, stream>>>(keys, thr, cnt, cand);
  k_sort   <<<NT, 512, 0, stream>>>(clean, patch, cnt, cand, clsArr, boxesK, clsK, validK);
  k_ioumat <<<dim3(16, NT), 256, 0, stream>>>(boxesK, clsK, sup);
  k_greedy <<<NT, 64, 0, stream>>>(sup, validK, keepw);
  k_loss   <<<dim3(8, NB), 256, 0, stream>>>(boxesK, clsK, keepw, part);
  k_final  <<<1, 64, 0, stream>>>(part, out);
}

// Round 3
// 481.607 us; speedup vs baseline: 1.3131x; 1.3131x over previous
//
#include <hip/hip_runtime.h>

// Pipeline: k_zero -> k_score(+hist, wave-aggregated) -> k_select -> k_compact
//           -> k_sort -> k_ioumat -> k_greedy -> k_loss -> k_final

static constexpr int NB   = 8;
static constexpr int NA   = 25200;
static constexpr int NCLS = 80;
static constexpr int CH   = 85;
static constexpr int NT   = 16;    // 8 clean + 8 patch tasks
static constexpr int KMAX = 1024;
static constexpr int NBIN = 65536; // 16-bit prefix histogram
static constexpr int CAP  = 4096;  // candidate buffer per task
static constexpr int CPAD = 32;    // counter padding (u32s) -> one 128B line each

// workspace byte offsets (all 16B aligned)
static constexpr size_t OFF_KEYS = 0;                                   // 1,612,800
static constexpr size_t OFF_CLS  = OFF_KEYS + (size_t)NT * NA * 4;      // 1,612,800
static constexpr size_t OFF_BOX  = OFF_CLS  + (size_t)NT * NA * 4;      // 262,144
static constexpr size_t OFF_CLSK = OFF_BOX  + (size_t)NT * KMAX * 16;   // 65,536
static constexpr size_t OFF_VALK = OFF_CLSK + (size_t)NT * KMAX * 4;    // 65,536
static constexpr size_t OFF_KEEP = OFF_VALK + (size_t)NT * KMAX * 4;    // 2,048
static constexpr size_t OFF_SUP  = OFF_KEEP + (size_t)NT * 16 * 8;      // 2,097,152
static constexpr size_t OFF_PART = OFF_SUP  + (size_t)NT * KMAX * 16 * 8; // 512
static constexpr size_t OFF_HIST = OFF_PART + 512;                      // 4,194,304
static constexpr size_t OFF_CNT  = OFF_HIST + (size_t)NT * NBIN * 4;    // NT*2*CPAD*4 = 4,096
static constexpr size_t OFF_THR  = OFF_CNT  + (size_t)NT * 2 * CPAD * 4; // 128
static constexpr size_t OFF_CAND = OFF_THR  + 128;                      // 524,288
// total ~10.5 MB

__device__ __forceinline__ unsigned okey(float f) {
  unsigned u = __float_as_uint(f);
  return (u & 0x80000000u) ? ~u : (u | 0x80000000u);
}

// ---------------- K0: zero hist + counters ----------------
__global__ __launch_bounds__(256) void k_zero(uint4* __restrict__ hist4,
                                              unsigned* __restrict__ cnt) {
  const int n = NT * NBIN / 4;
  for (int i = blockIdx.x * 256 + threadIdx.x; i < n; i += gridDim.x * 256)
    hist4[i] = make_uint4(0u, 0u, 0u, 0u);
  if (blockIdx.x == 0)
    for (int j = threadIdx.x; j < NT * 2 * CPAD; j += 256) cnt[j] = 0u;
}

// ---------------- K1: per-anchor score/class + histogram ----------------
// 64 anchors / block (21.8KB LDS -> 7 blocks/CU), 4 threads per anchor.
__global__ __launch_bounds__(256) void k_score(const float* __restrict__ clean,
                                               const float* __restrict__ patch,
                                               unsigned* __restrict__ keys,
                                               int* __restrict__ clsArr,
                                               unsigned* __restrict__ hist) {
#pragma clang fp contract(off)
  const int t  = blockIdx.y;
  const int a0 = blockIdx.x * 64;
  const int nA = (NA - a0 < 64) ? (NA - a0) : 64;
  const float conf_th = (t < 8) ? 0.25f : 0.001f;
  const float* __restrict__ src = ((t < 8) ? clean : patch) + (size_t)(t & 7) * NA * CH;
  __shared__ float rows[64 * CH];
  const float4* g4 = (const float4*)(src + (size_t)a0 * CH);
  float4* s4 = (float4*)rows;
  const int n4 = (nA * CH) >> 2;
  for (int i = threadIdx.x; i < n4; i += 256) s4[i] = g4[i];
  __syncthreads();

  const int ar = threadIdx.x >> 2;  // anchor within tile
  const int q  = threadIdx.x & 3;   // class stripe
  bool invalid_flag = false;
  unsigned* ht = hist + (size_t)t * NBIN;
  if (ar < nA) {
    const float* r = rows + ar * CH;
    const float obj = r[4];
    const int c0 = q * 20;
    float best = r[5 + c0] * obj;  // products first (matches ref argmax over cls_conf)
    int bc = c0;
    for (int c = c0 + 1; c < c0 + 20; ++c) {
      float v = r[5 + c] * obj;
      if (v > best) { best = v; bc = c; }
    }
    // merge partials (distance 2 then 1); tie -> lower class index (argmax-first)
    {
      float b2 = __shfl_down(best, 2); int c2 = __shfl_down(bc, 2);
      if (b2 > best || (b2 == best && c2 < bc)) { best = b2; bc = c2; }
      float b1 = __shfl_down(best, 1); int c1 = __shfl_down(bc, 1);
      if (b1 > best || (b1 == best && c1 < bc)) { best = b1; bc = c1; }
    }
    if (q == 0) {
      const bool valid = (obj > conf_th) && (best > conf_th);
      const float score = valid ? best : -1e30f;
      const unsigned key = okey(score);
      const int a = a0 + ar;
      keys[(size_t)t * NA + a]   = key;
      clsArr[(size_t)t * NA + a] = bc;
      if (valid) atomicAdd(&ht[key >> 16], 1u);
      else invalid_flag = true;
    }
  }
  // wave-aggregated hot-bin update for invalid anchors (all share one key)
  unsigned long long m = __ballot(invalid_flag);
  if (m) {
    const int lane = threadIdx.x & 63;
    if (lane == (int)__ffsll(m) - 1) {
      const unsigned invBin = okey(-1e30f) >> 16;
      atomicAdd(&ht[invBin], (unsigned)__popcll(m));
    }
  }
}

// ---------------- K2: exact threshold bin via hierarchical suffix scan ----------------
__global__ __launch_bounds__(256) void k_select(const unsigned* __restrict__ hist,
                                                unsigned* __restrict__ thr) {
  const int t = blockIdx.x;
  const unsigned K = (t < 8) ? 512u : 1024u;
  const unsigned* h = hist + (size_t)t * NBIN;
  __shared__ unsigned s[256];
  __shared__ int s_chunk;
  __shared__ unsigned s_accAbove;
  const int tid = threadIdx.x;
  {
    const uint4* h4 = (const uint4*)(h + tid * 256);
    unsigned sum = 0;
    for (int i = 0; i < 64; ++i) { uint4 v = h4[i]; sum += v.x + v.y + v.z + v.w; }
    s[tid] = sum;
  }
  __syncthreads();
  for (int off = 1; off < 256; off <<= 1) {
    unsigned v = s[tid];
    if (tid + off < 256) v += s[tid + off];
    __syncthreads();
    s[tid] = v;
    __syncthreads();
  }
  {
    bool pred = s[tid] >= K;
    bool next = (tid == 255) ? false : (s[tid + 1] >= K);
    if (pred && !next) {
      s_chunk = tid;
      s_accAbove = (tid == 255) ? 0u : s[tid + 1];
    }
  }
  __syncthreads();
  const int c = s_chunk;
  const unsigned accAbove = s_accAbove;
  s[tid] = h[c * 256 + tid];
  __syncthreads();
  for (int off = 1; off < 256; off <<= 1) {
    unsigned v = s[tid];
    if (tid + off < 256) v += s[tid + off];
    __syncthreads();
    s[tid] = v;
    __syncthreads();
  }
  {
    bool pred = accAbove + s[tid] >= K;
    bool next = (tid == 255) ? false : (accAbove + s[tid + 1] >= K);
    if (pred && !next) thr[t] = (unsigned)(c * 256 + tid);
  }
}

// ---------------- K3: compact candidates (wave-aggregated atomics) ----------------
__global__ __launch_bounds__(256) void k_compact(const unsigned* __restrict__ keys,
                                                 const unsigned* __restrict__ thr,
                                                 unsigned* __restrict__ cnt,
                                                 unsigned long long* __restrict__ cand) {
  const int t = blockIdx.y;
  const int a = blockIdx.x * 256 + threadIdx.x;
  const unsigned B = thr[t];
  unsigned key = 0u, p = 0u;
  const bool inb = (a < NA);
  if (inb) { key = keys[(size_t)t * NA + a]; p = key >> 16; }
  const bool hi = inb && (p > B);
  const bool eq = inb && (p == B);
  const unsigned long long item =
      ((unsigned long long)key << 32) | (unsigned)(~(unsigned)a);
  const int lane = threadIdx.x & 63;
  const unsigned long long lowmask =
      (lane == 0) ? 0ull : (0xFFFFFFFFFFFFFFFFull >> (64 - lane));
  unsigned long long mh = __ballot(hi);
  if (mh) {
    const int leader = (int)__ffsll(mh) - 1;
    unsigned base = 0;
    if (lane == leader) base = atomicAdd(&cnt[(t * 2 + 0) * CPAD], (unsigned)__popcll(mh));
    base = __shfl(base, leader);
    if (hi) {
      unsigned pos = base + (unsigned)__popcll(mh & lowmask);
      if (pos < 1024u) cand[(size_t)t * CAP + pos] = item;
    }
  }
  unsigned long long me = __ballot(eq);
  if (me) {
    const int leader = (int)__ffsll(me) - 1;
    unsigned base = 0;
    if (lane == leader) base = atomicAdd(&cnt[(t * 2 + 1) * CPAD], (unsigned)__popcll(me));
    base = __shfl(base, leader);
    if (eq) {
      unsigned pos = base + (unsigned)__popcll(me & lowmask);
      if (pos < (unsigned)(CAP - 1024)) cand[(size_t)t * CAP + 1024 + pos] = item;
    }
  }
}

// ---------------- K4: bitonic sort candidates + gather top-K ----------------
__global__ __launch_bounds__(512) void k_sort(const float* __restrict__ clean,
                                              const float* __restrict__ patch,
                                              const unsigned* __restrict__ cnt,
                                              const unsigned long long* __restrict__ cand,
                                              const int* __restrict__ clsArr,
                                              float* __restrict__ boxesK,
                                              int* __restrict__ clsK,
                                              int* __restrict__ validK) {
#pragma clang fp contract(off)
  const int t = blockIdx.x;
  const int K = (t < 8) ? 512 : 1024;
  const float conf_th = (t < 8) ? 0.25f : 0.001f;
  __shared__ unsigned long long buf[CAP];
  const unsigned nHi = min(cnt[(t * 2 + 0) * CPAD], 1024u);
  const unsigned nEq = min(cnt[(t * 2 + 1) * CPAD], (unsigned)(CAP - 1024));
  const unsigned long long* cd = cand + (size_t)t * CAP;
  for (int i = threadIdx.x; i < CAP; i += 512) {
    unsigned long long v = 0ull;
    if (i < 1024) { if ((unsigned)i < nHi) v = cd[i]; }
    else          { if ((unsigned)(i - 1024) < nEq) v = cd[i]; }
    buf[i] = v;
  }
  __syncthreads();
  // bitonic sort descending; equal keys -> larger ~idx (= smaller idx) first
  for (int kk2 = 2; kk2 <= CAP; kk2 <<= 1) {
    for (int j = kk2 >> 1; j > 0; j >>= 1) {
      for (int i = threadIdx.x; i < CAP; i += 512) {
        int ixj = i ^ j;
        if (ixj > i) {
          unsigned long long a = buf[i], b = buf[ixj];
          bool desc = ((i & kk2) == 0);
          if (desc ? (a < b) : (a > b)) { buf[i] = b; buf[ixj] = a; }
        }
      }
      __syncthreads();
    }
  }
  const float* __restrict__ src = ((t < 8) ? clean : patch) + (size_t)(t & 7) * NA * CH;
  const unsigned vkey = okey(conf_th);
  for (int k = threadIdx.x; k < K; k += 512) {
    unsigned long long v = buf[k];
    unsigned key = (unsigned)(v >> 32);
    int idx = (int)(~(unsigned)(v & 0xFFFFFFFFull));
    const float* r = src + (size_t)idx * CH;
    float cx = r[0], cy = r[1], w = r[2], h = r[3];
    float hw = w * 0.5f, hh = h * 0.5f;
    float* bo = boxesK + ((size_t)t * KMAX + k) * 4;
    bo[0] = cx - hw; bo[1] = cy - hh; bo[2] = cx + hw; bo[3] = cy + hh;
    clsK[t * KMAX + k]   = clsArr[(size_t)t * NA + idx];
    validK[t * KMAX + k] = (key > vkey) ? 1 : 0;
  }
}

// ---------------- K5: suppression bit-matrix ----------------
__global__ __launch_bounds__(256) void k_ioumat(const float* __restrict__ boxesK,
                                                const int* __restrict__ clsK,
                                                unsigned long long* __restrict__ sup) {
#pragma clang fp contract(off)
  const int t  = blockIdx.y;
  const int K  = (t < 8) ? 512 : 1024;
  const int lw = (t < 8) ? 3 : 4;
  const int nw = 1 << lw;
  __shared__ float X1[KMAX], Y1[KMAX], X2[KMAX], Y2[KMAX], AR[KMAX];
  for (int i = threadIdx.x; i < K; i += 256) {
    const float* bo = boxesK + ((size_t)t * KMAX + i) * 4;
    float off = (float)clsK[t * KMAX + i] * 4096.0f;
    float x1 = bo[0] + off, y1 = bo[1] + off, x2 = bo[2] + off, y2 = bo[3] + off;
    X1[i] = x1; Y1[i] = y1; X2[i] = x2; Y2[i] = y2;
    AR[i] = (x2 - x1) * (y2 - y1);
  }
  __syncthreads();
  const int total = K * nw;
  unsigned long long* supt = sup + (size_t)t * (KMAX * 16);
  for (int widx = blockIdx.x * 256 + threadIdx.x; widx < total; widx += 16 * 256) {
    int i  = widx >> lw;
    int wc = widx & (nw - 1);
    float x1i = X1[i], y1i = Y1[i], x2i = X2[i], y2i = Y2[i], ai = AR[i];
    unsigned long long m = 0ull;
    int jbase = wc << 6;
    for (int l = 0; l < 64; ++l) {
      int j = jbase + l;
      if (j > i) {
        float tlx = fmaxf(x1i, X1[j]);
        float tly = fmaxf(y1i, Y1[j]);
        float brx = fminf(x2i, X2[j]);
        float bry = fminf(y2i, Y2[j]);
        float w = fmaxf(brx - tlx, 0.0f);
        float h = fmaxf(bry - tly, 0.0f);
        float inter = w * h;
        float uni = (ai + AR[j]) - inter;
        uni = (uni > 0.0f) ? uni : 1.0f;
        float iou = inter / uni;
        if (iou > 0.45f) m |= (1ull << l);
      }
    }
    supt[(size_t)i * nw + wc] = m;
  }
}

// ---------------- K6: greedy NMS, word-blocked, batched-prefetch chain ----------------
__global__ __launch_bounds__(64) void k_greedy(const unsigned long long* __restrict__ sup,
                                               const int* __restrict__ validK,
                                               unsigned long long* __restrict__ keepw) {
  const int t  = blockIdx.x;
  const int K  = (t < 8) ? 512 : 1024;
  const int nw = K >> 6;
  const int lane = threadIdx.x;
  __shared__ unsigned long long buf[KMAX];
  const unsigned long long* base = sup + (size_t)t * (KMAX * 16);
  unsigned long long remv = 0ull;
  for (int W = 0; W < nw; ++W) {
    const uint4* g4 = (const uint4*)(base + (size_t)W * 64 * nw);
    uint4* b4 = (uint4*)buf;
    const int nq = nw >> 1;
    uint4 tmp4[8];
#pragma unroll
    for (int q = 0; q < 8; ++q) if (q < nq) tmp4[q] = g4[q * 64 + lane];
#pragma unroll
    for (int q = 0; q < 8; ++q) if (q < nq) b4[q * 64 + lane] = tmp4[q];
    __syncthreads();
    int v = validK[t * KMAX + W * 64 + lane];
    unsigned long long cur = __ballot(v != 0);
    cur &= ~__shfl(remv, W);
    // batched prefetch (16 rows) + register-only sequential greedy chain
    for (int rb = 0; rb < 64; rb += 16) {
      unsigned long long tm[16];
#pragma unroll
      for (int i = 0; i < 16; ++i) tm[i] = buf[(rb + i) * nw + W];
#pragma unroll
      for (int i = 0; i < 16; ++i) {
        unsigned long long msk = 0ull - ((cur >> (rb + i)) & 1ull);
        cur &= ~(tm[i] & msk);
      }
    }
    if (lane > W && lane < nw) {
      for (int r = 0; r < 64; ++r)
        if ((cur >> r) & 1ull) remv |= buf[r * nw + lane];
    }
    if (lane == 0) keepw[t * 16 + W] = cur;
    __syncthreads();
  }
}

// ---------------- K7: masked-max IoU loss partials ----------------
__global__ __launch_bounds__(256) void k_loss(const float* __restrict__ boxesK,
                                              const int* __restrict__ clsK,
                                              const unsigned long long* __restrict__ keepw,
                                              float* __restrict__ part) {
#pragma clang fp contract(off)
  const int img = blockIdx.y;
  const int chunk = blockIdx.x;
  const int tp = 8 + img;
  __shared__ float px1[KMAX], py1[KMAX], px2[KMAX], py2[KMAX], pa[KMAX];
  __shared__ int pcls[KMAX];
  __shared__ float red[256];
  for (int j = threadIdx.x; j < KMAX; j += 256) {
    const float* bo = boxesK + ((size_t)tp * KMAX + j) * 4;
    float x1 = bo[0] / 640.0f, y1 = bo[1] / 640.0f;
    float x2 = bo[2] / 640.0f, y2 = bo[3] / 640.0f;
    px1[j] = x1; py1[j] = y1; px2[j] = x2; py2[j] = y2;
    pa[j] = (x2 - x1) * (y2 - y1);
    int kept = (int)((keepw[tp * 16 + (j >> 6)] >> (j & 63)) & 1ull);
    pcls[j] = kept ? clsK[tp * KMAX + j] : -1;
  }
  __syncthreads();
  const int row = chunk * 64 + (threadIdx.x & 63);
  const int stripe = threadIdx.x >> 6;
  const int ck = (int)((keepw[img * 16 + (row >> 6)] >> (row & 63)) & 1ull);
  const float* bo = boxesK + ((size_t)img * KMAX + row) * 4;
  float cx1 = bo[0] / 640.0f, cy1 = bo[1] / 640.0f;
  float cx2 = bo[2] / 640.0f, cy2 = bo[3] / 640.0f;
  float ca = (cx2 - cx1) * (cy2 - cy1);
  const int ccls = clsK[img * KMAX + row];
  float m = 0.0f;
  if (ck) {
    const int j0 = stripe * 256;
    for (int j = j0; j < j0 + 256; ++j) {
      if (pcls[j] == ccls) {
        float tlx = fmaxf(cx1, px1[j]);
        float tly = fmaxf(cy1, py1[j]);
        float brx = fminf(cx2, px2[j]);
        float bry = fminf(cy2, py2[j]);
        float w = fmaxf(brx - tlx, 0.0f);
        float h = fmaxf(bry - tly, 0.0f);
        float inter = w * h;
        float uni = (ca + pa[j]) - inter;
        uni = (uni > 0.0f) ? uni : 1.0f;
        m = fmaxf(m, inter / uni);
      }
    }
  }
  red[threadIdx.x] = m;
  __syncthreads();
  if (threadIdx.x < 64) {
    float mm = fmaxf(fmaxf(red[threadIdx.x], red[threadIdx.x + 64]),
                     fmaxf(red[threadIdx.x + 128], red[threadIdx.x + 192]));
    float sv = ck ? mm : 0.0f;
    float nv = ck ? 1.0f : 0.0f;
    for (int off = 32; off > 0; off >>= 1) {
      sv += __shfl_down(sv, off);
      nv += __shfl_down(nv, off);
    }
    if (threadIdx.x == 0) {
      int b = img * 8 + chunk;
      part[b * 2 + 0] = sv;
      part[b * 2 + 1] = nv;
    }
  }
}

// ---------------- K8: deterministic final reduce ----------------
__global__ __launch_bounds__(64) void k_final(const float* __restrict__ part,
                                              float* __restrict__ out) {
  int lane = threadIdx.x;
  float sv = part[lane * 2 + 0];
  float nv = part[lane * 2 + 1];
  for (int off = 32; off > 0; off >>= 1) {
    sv += __shfl_down(sv, off);
    nv += __shfl_down(nv, off);
  }
  if (lane == 0) out[0] = (nv > 0.0f) ? (1.0f - sv / fmaxf(nv, 1.0f)) : 1.0f;
}

extern "C" void kernel_launch(void* const* d_in, const int* in_sizes, int n_in,
                              void* d_out, int out_size, void* d_ws, size_t ws_size,
                              hipStream_t stream) {
  const float* clean = (const float*)d_in[0];
  const float* patch = (const float*)d_in[1];
  char* ws = (char*)d_ws;
  unsigned* keys            = (unsigned*)(ws + OFF_KEYS);
  int* clsArr               = (int*)(ws + OFF_CLS);
  float* boxesK             = (float*)(ws + OFF_BOX);
  int* clsK                 = (int*)(ws + OFF_CLSK);
  int* validK               = (int*)(ws + OFF_VALK);
  unsigned long long* keepw = (unsigned long long*)(ws + OFF_KEEP);
  unsigned long long* sup   = (unsigned long long*)(ws + OFF_SUP);
  float* part               = (float*)(ws + OFF_PART);
  unsigned* hist            = (unsigned*)(ws + OFF_HIST);
  unsigned* cnt             = (unsigned*)(ws + OFF_CNT);
  unsigned* thr             = (unsigned*)(ws + OFF_THR);
  unsigned long long* cand  = (unsigned long long*)(ws + OFF_CAND);
  float* out                = (float*)d_out;

  k_zero   <<<256, 256, 0, stream>>>((uint4*)hist, cnt);
  k_score  <<<dim3((NA + 63) / 64, NT), 256, 0, stream>>>(clean, patch, keys, clsArr, hist);
  k_select <<<NT, 256, 0, stream>>>(hist, thr);
  k_compact<<<dim3((NA + 255) / 256, NT), 256, 0, stream>>>(keys, thr, cnt, cand);
  k_sort   <<<NT, 512, 0, stream>>>(clean, patch, cnt, cand, clsArr, boxesK, clsK, validK);
  k_ioumat <<<dim3(16, NT), 256, 0, stream>>>(boxesK, clsK, sup);
  k_greedy <<<NT, 64, 0, stream>>>(sup, validK, keepw);
  k_loss   <<<dim3(8, NB), 256, 0, stream>>>(boxesK, clsK, keepw, part);
  k_final  <<<1, 64, 0, stream>>>(part, out);
}

// Round 4
// 414.944 us; speedup vs baseline: 1.5241x; 1.1607x over previous
//
#include <hip/hip_runtime.h>

// Pipeline: k_zero -> k_score(+hist) -> k_select -> k_compact -> k_sort
//           -> k_ioumat(+diag) -> k_greedy(diag+sparse gather) -> k_loss -> k_final

static constexpr int NB   = 8;
static constexpr int NA   = 25200;
static constexpr int NCLS = 80;
static constexpr int CH   = 85;
static constexpr int NT   = 16;    // 8 clean + 8 patch tasks
static constexpr int KMAX = 1024;
static constexpr int NBIN = 32768; // 15-bit prefix histogram
static constexpr int PSH  = 17;    // key >> PSH = bin
static constexpr int CAP  = 2048;  // candidate buffer per task (hi[0,1024) eq[1024,2048))
static constexpr int CPAD = 32;    // counter padding (u32) -> one 128B line each

// workspace byte offsets (all 16B aligned)
static constexpr size_t OFF_KEYS = 0;                                    // 1,612,800
static constexpr size_t OFF_CLS  = OFF_KEYS + (size_t)NT * NA * 4;       // 1,612,800
static constexpr size_t OFF_BOX  = OFF_CLS  + (size_t)NT * NA * 4;       // 262,144
static constexpr size_t OFF_CLSK = OFF_BOX  + (size_t)NT * KMAX * 16;    // 65,536
static constexpr size_t OFF_VALK = OFF_CLSK + (size_t)NT * KMAX * 4;     // 65,536
static constexpr size_t OFF_KEEP = OFF_VALK + (size_t)NT * KMAX * 4;     // 2,048
static constexpr size_t OFF_SUP  = OFF_KEEP + (size_t)NT * 16 * 8;       // 2,097,152
static constexpr size_t OFF_DIAG = OFF_SUP  + (size_t)NT * KMAX * 16 * 8;// 131,072
static constexpr size_t OFF_PART = OFF_DIAG + (size_t)NT * KMAX * 8;     // 512
static constexpr size_t OFF_HIST = OFF_PART + 512;                       // 2,097,152
static constexpr size_t OFF_CNT  = OFF_HIST + (size_t)NT * NBIN * 4;     // 4,096
static constexpr size_t OFF_THR  = OFF_CNT  + (size_t)NT * 2 * CPAD * 4; // 128
static constexpr size_t OFF_CAND = OFF_THR  + 128;                       // 262,144
// total ~8.3 MB

__device__ __forceinline__ unsigned okey(float f) {
  unsigned u = __float_as_uint(f);
  return (u & 0x80000000u) ? ~u : (u | 0x80000000u);
}

// ---------------- K0: zero hist + counters ----------------
__global__ __launch_bounds__(256) void k_zero(uint4* __restrict__ hist4,
                                              unsigned* __restrict__ cnt) {
  const int n = NT * NBIN / 4;
  for (int i = blockIdx.x * 256 + threadIdx.x; i < n; i += gridDim.x * 256)
    hist4[i] = make_uint4(0u, 0u, 0u, 0u);
  if (blockIdx.x == 0)
    for (int j = threadIdx.x; j < NT * 2 * CPAD; j += 256) cnt[j] = 0u;
}

// ---------------- K1: per-anchor score/class + histogram ----------------
// 64 anchors / block (21.8KB LDS -> 7 blocks/CU), 4 threads per anchor.
__global__ __launch_bounds__(256) void k_score(const float* __restrict__ clean,
                                               const float* __restrict__ patch,
                                               unsigned* __restrict__ keys,
                                               int* __restrict__ clsArr,
                                               unsigned* __restrict__ hist) {
#pragma clang fp contract(off)
  const int t  = blockIdx.y;
  const int a0 = blockIdx.x * 64;
  const int nA = (NA - a0 < 64) ? (NA - a0) : 64;
  const float conf_th = (t < 8) ? 0.25f : 0.001f;
  const float* __restrict__ src = ((t < 8) ? clean : patch) + (size_t)(t & 7) * NA * CH;
  __shared__ float rows[64 * CH];
  const float4* g4 = (const float4*)(src + (size_t)a0 * CH);
  float4* s4 = (float4*)rows;
  const int n4 = (nA * CH) >> 2;
  for (int i = threadIdx.x; i < n4; i += 256) s4[i] = g4[i];
  __syncthreads();

  const int ar = threadIdx.x >> 2;  // anchor within tile
  const int q  = threadIdx.x & 3;   // class stripe
  bool invalid_flag = false;
  unsigned* ht = hist + (size_t)t * NBIN;
  if (ar < nA) {
    const float* r = rows + ar * CH;
    const float obj = r[4];
    const int c0 = q * 20;
    float best = r[5 + c0] * obj;  // products first (matches ref argmax over cls_conf)
    int bc = c0;
    for (int c = c0 + 1; c < c0 + 20; ++c) {
      float v = r[5 + c] * obj;
      if (v > best) { best = v; bc = c; }
    }
    {
      float b2 = __shfl_down(best, 2); int c2 = __shfl_down(bc, 2);
      if (b2 > best || (b2 == best && c2 < bc)) { best = b2; bc = c2; }
      float b1 = __shfl_down(best, 1); int c1 = __shfl_down(bc, 1);
      if (b1 > best || (b1 == best && c1 < bc)) { best = b1; bc = c1; }
    }
    if (q == 0) {
      const bool valid = (obj > conf_th) && (best > conf_th);
      const float score = valid ? best : -1e30f;
      const unsigned key = okey(score);
      const int a = a0 + ar;
      keys[(size_t)t * NA + a]   = key;
      clsArr[(size_t)t * NA + a] = bc;
      if (valid) atomicAdd(&ht[key >> PSH], 1u);
      else invalid_flag = true;
    }
  }
  // wave-aggregated hot-bin update for invalid anchors (all share one key)
  unsigned long long m = __ballot(invalid_flag);
  if (m) {
    const int lane = threadIdx.x & 63;
    if (lane == (int)__ffsll(m) - 1) {
      const unsigned invBin = okey(-1e30f) >> PSH;
      atomicAdd(&ht[invBin], (unsigned)__popcll(m));
    }
  }
}

// ---------------- K2: exact threshold bin (256 chunks x 128 bins) ----------------
__global__ __launch_bounds__(256) void k_select(const unsigned* __restrict__ hist,
                                                unsigned* __restrict__ thr) {
  const int t = blockIdx.x;
  const unsigned K = (t < 8) ? 512u : 1024u;
  const unsigned* h = hist + (size_t)t * NBIN;
  __shared__ unsigned s[256];
  __shared__ int s_chunk;
  __shared__ unsigned s_accAbove;
  const int tid = threadIdx.x;
  {
    const uint4* h4 = (const uint4*)(h + tid * 128);
    unsigned sum = 0;
    for (int i = 0; i < 32; ++i) { uint4 v = h4[i]; sum += v.x + v.y + v.z + v.w; }
    s[tid] = sum;
  }
  __syncthreads();
  for (int off = 1; off < 256; off <<= 1) {
    unsigned v = s[tid];
    if (tid + off < 256) v += s[tid + off];
    __syncthreads();
    s[tid] = v;
    __syncthreads();
  }
  {
    bool pred = s[tid] >= K;
    bool next = (tid == 255) ? false : (s[tid + 1] >= K);
    if (pred && !next) {
      s_chunk = tid;
      s_accAbove = (tid == 255) ? 0u : s[tid + 1];
    }
  }
  __syncthreads();
  const int c = s_chunk;
  const unsigned accAbove = s_accAbove;
  s[tid] = (tid < 128) ? h[c * 128 + tid] : 0u;
  __syncthreads();
  for (int off = 1; off < 256; off <<= 1) {
    unsigned v = s[tid];
    if (tid + off < 256) v += s[tid + off];
    __syncthreads();
    s[tid] = v;
    __syncthreads();
  }
  {
    bool pred = accAbove + s[tid] >= K;
    bool next = (tid == 255) ? false : (accAbove + s[tid + 1] >= K);
    if (pred && !next) thr[t] = (unsigned)(c * 128 + tid);
  }
}

// ---------------- K3: compact candidates (wave-aggregated atomics) ----------------
__global__ __launch_bounds__(256) void k_compact(const unsigned* __restrict__ keys,
                                                 const unsigned* __restrict__ thr,
                                                 unsigned* __restrict__ cnt,
                                                 unsigned long long* __restrict__ cand) {
  const int t = blockIdx.y;
  const int a = blockIdx.x * 256 + threadIdx.x;
  const unsigned B = thr[t];
  unsigned key = 0u, p = 0u;
  const bool inb = (a < NA);
  if (inb) { key = keys[(size_t)t * NA + a]; p = key >> PSH; }
  const bool hi = inb && (p > B);
  const bool eq = inb && (p == B);
  const unsigned long long item =
      ((unsigned long long)key << 32) | (unsigned)(~(unsigned)a);
  const int lane = threadIdx.x & 63;
  const unsigned long long lowmask =
      (lane == 0) ? 0ull : (0xFFFFFFFFFFFFFFFFull >> (64 - lane));
  unsigned long long mh = __ballot(hi);
  if (mh) {
    const int leader = (int)__ffsll(mh) - 1;
    unsigned base = 0;
    if (lane == leader) base = atomicAdd(&cnt[(t * 2 + 0) * CPAD], (unsigned)__popcll(mh));
    base = __shfl(base, leader);
    if (hi) {
      unsigned pos = base + (unsigned)__popcll(mh & lowmask);
      if (pos < 1024u) cand[(size_t)t * CAP + pos] = item;
    }
  }
  unsigned long long me = __ballot(eq);
  if (me) {
    const int leader = (int)__ffsll(me) - 1;
    unsigned base = 0;
    if (lane == leader) base = atomicAdd(&cnt[(t * 2 + 1) * CPAD], (unsigned)__popcll(me));
    base = __shfl(base, leader);
    if (eq) {
      unsigned pos = base + (unsigned)__popcll(me & lowmask);
      if (pos < 1024u) cand[(size_t)t * CAP + 1024 + pos] = item;
    }
  }
}

// ---------------- K4: bitonic sort candidates + gather top-K ----------------
__global__ __launch_bounds__(512) void k_sort(const float* __restrict__ clean,
                                              const float* __restrict__ patch,
                                              const unsigned* __restrict__ cnt,
                                              const unsigned long long* __restrict__ cand,
                                              const int* __restrict__ clsArr,
                                              float* __restrict__ boxesK,
                                              int* __restrict__ clsK,
                                              int* __restrict__ validK) {
#pragma clang fp contract(off)
  const int t = blockIdx.x;
  const int K = (t < 8) ? 512 : 1024;
  const float conf_th = (t < 8) ? 0.25f : 0.001f;
  __shared__ unsigned long long buf[CAP];
  const unsigned nHi = min(cnt[(t * 2 + 0) * CPAD], 1024u);
  const unsigned nEq = min(cnt[(t * 2 + 1) * CPAD], 1024u);
  const unsigned long long* cd = cand + (size_t)t * CAP;
  for (int i = threadIdx.x; i < CAP; i += 512) {
    unsigned long long v = 0ull;
    if (i < 1024) { if ((unsigned)i < nHi) v = cd[i]; }
    else          { if ((unsigned)(i - 1024) < nEq) v = cd[i]; }
    buf[i] = v;
  }
  __syncthreads();
  // bitonic sort descending; equal keys -> larger ~idx (= smaller idx) first
  for (int kk2 = 2; kk2 <= CAP; kk2 <<= 1) {
    for (int j = kk2 >> 1; j > 0; j >>= 1) {
      for (int i = threadIdx.x; i < CAP; i += 512) {
        int ixj = i ^ j;
        if (ixj > i) {
          unsigned long long a = buf[i], b = buf[ixj];
          bool desc = ((i & kk2) == 0);
          if (desc ? (a < b) : (a > b)) { buf[i] = b; buf[ixj] = a; }
        }
      }
      __syncthreads();
    }
  }
  const float* __restrict__ src = ((t < 8) ? clean : patch) + (size_t)(t & 7) * NA * CH;
  const unsigned vkey = okey(conf_th);
  for (int k = threadIdx.x; k < K; k += 512) {
    unsigned long long v = buf[k];
    unsigned key = (unsigned)(v >> 32);
    int idx = (int)(~(unsigned)(v & 0xFFFFFFFFull));
    if (idx < 0) idx = 0;  // padding entries (key 0) are masked downstream
    const float* r = src + (size_t)idx * CH;
    float cx = r[0], cy = r[1], w = r[2], h = r[3];
    float hw = w * 0.5f, hh = h * 0.5f;
    float* bo = boxesK + ((size_t)t * KMAX + k) * 4;
    bo[0] = cx - hw; bo[1] = cy - hh; bo[2] = cx + hw; bo[3] = cy + hh;
    clsK[t * KMAX + k]   = clsArr[(size_t)t * NA + idx];
    validK[t * KMAX + k] = (key > vkey) ? 1 : 0;
  }
}

// ---------------- K5: suppression bit-matrix (upper triangle only) + diag ----------------
__global__ __launch_bounds__(256) void k_ioumat(const float* __restrict__ boxesK,
                                                const int* __restrict__ clsK,
                                                unsigned long long* __restrict__ sup,
                                                unsigned long long* __restrict__ diag) {
#pragma clang fp contract(off)
  const int t  = blockIdx.y;
  const int K  = (t < 8) ? 512 : 1024;
  const int lw = (t < 8) ? 3 : 4;
  const int nw = 1 << lw;
  // padded SoA: index i + (i>>6) breaks the stride-64 16-way bank conflict
  __shared__ float X1[KMAX + 16], Y1[KMAX + 16], X2[KMAX + 16], Y2[KMAX + 16], AR[KMAX + 16];
  for (int i = threadIdx.x; i < K; i += 256) {
    const float* bo = boxesK + ((size_t)t * KMAX + i) * 4;
    float off = (float)clsK[t * KMAX + i] * 4096.0f;
    float x1 = bo[0] + off, y1 = bo[1] + off, x2 = bo[2] + off, y2 = bo[3] + off;
    const int ip = i + (i >> 6);
    X1[ip] = x1; Y1[ip] = y1; X2[ip] = x2; Y2[ip] = y2;
    AR[ip] = (x2 - x1) * (y2 - y1);
  }
  __syncthreads();
  const int total = K * nw;
  unsigned long long* supt = sup + (size_t)t * (KMAX * 16);
  for (int widx = blockIdx.x * 256 + threadIdx.x; widx < total; widx += 16 * 256) {
    int i  = widx >> lw;
    int wc = widx & (nw - 1);
    if (wc < (i >> 6)) continue;  // lower triangle never read
    const int ipi = i + (i >> 6);
    float x1i = X1[ipi], y1i = Y1[ipi], x2i = X2[ipi], y2i = Y2[ipi], ai = AR[ipi];
    unsigned long long m = 0ull;
    const int jb = (wc << 6) + wc;  // padded base for j = wc*64 + l
    for (int l = 0; l < 64; ++l) {
      int j = (wc << 6) + l;
      if (j > i) {
        int jp = jb + l;
        float tlx = fmaxf(x1i, X1[jp]);
        float tly = fmaxf(y1i, Y1[jp]);
        float brx = fminf(x2i, X2[jp]);
        float bry = fminf(y2i, Y2[jp]);
        float w = fmaxf(brx - tlx, 0.0f);
        float h = fmaxf(bry - tly, 0.0f);
        float inter = w * h;
        float uni = (ai + AR[jp]) - inter;
        uni = (uni > 0.0f) ? uni : 1.0f;
        float iou = inter / uni;
        if (iou > 0.45f) m |= (1ull << l);
      }
    }
    supt[(size_t)i * nw + wc] = m;
    if (wc == (i >> 6)) diag[(size_t)t * KMAX + i] = m;
  }
}

// ---------------- K6: greedy NMS — LDS diag chain + sparse kept-row gather ----------------
__global__ __launch_bounds__(64) void k_greedy(const unsigned long long* __restrict__ sup,
                                               const unsigned long long* __restrict__ diag,
                                               const int* __restrict__ validK,
                                               unsigned long long* __restrict__ keepw) {
  const int t  = blockIdx.x;
  const int K  = (t < 8) ? 512 : 1024;
  const int lw = (t < 8) ? 3 : 4;
  const int nw = 1 << lw;
  const int lane = threadIdx.x;
  __shared__ unsigned long long sdiag[KMAX];
  const unsigned long long* dg = diag + (size_t)t * KMAX;
  for (int i = lane; i < K; i += 64) sdiag[i] = dg[i];
  // prefetch all valid flags (batched, 1 latency), ballots into per-lane register
  int v16[16];
#pragma unroll
  for (int W = 0; W < 16; ++W)
    v16[W] = (W < nw) ? validK[t * KMAX + W * 64 + lane] : 0;
  unsigned long long vkeep = 0ull;
#pragma unroll
  for (int W = 0; W < 16; ++W)
    if (W < nw) {
      unsigned long long bl = __ballot(v16[W] != 0);
      if (lane == W) vkeep = bl;
    }
  __syncthreads();
  const int w = lane & (nw - 1);   // word this lane accumulates
  const int b = lane >> lw;        // row-slice this lane gathers
  const unsigned long long* base = sup + (size_t)t * (KMAX * 16);
  unsigned long long remv = 0ull;  // suppression for word w (same value across each w-class)
  for (int W = 0; W < nw; ++W) {
    unsigned long long cur = __shfl(vkeep, W) & ~__shfl(remv, W);
    // in-word sequential greedy on the LDS diagonal block (batched prefetch)
    for (int rb = 0; rb < 64; rb += 16) {
      unsigned long long tm[16];
#pragma unroll
      for (int i2 = 0; i2 < 16; ++i2) tm[i2] = sdiag[W * 64 + rb + i2];
#pragma unroll
      for (int i2 = 0; i2 < 16; ++i2) {
        unsigned long long msk = 0ull - ((cur >> (rb + i2)) & 1ull);
        cur &= ~(tm[i2] & msk);
      }
    }
    if (lane == 0) keepw[t * 16 + W] = cur;
    // sparse forward suppression: only kept rows' words > W, batched independent loads
    if (W + 1 < nw) {
      const int r0 = b * nw;  // this lane's row slice [r0, r0+nw)
      unsigned long long vv[16];
#pragma unroll
      for (int j = 0; j < 16; ++j) {
        bool take = (j < nw) && (w > W) && ((cur >> (r0 + j)) & 1ull);
        vv[j] = take ? base[(size_t)(W * 64 + r0 + j) * nw + w] : 0ull;
      }
      unsigned long long part = 0ull;
#pragma unroll
      for (int j = 0; j < 16; ++j) part |= vv[j];
      for (int s = nw; s < 64; s <<= 1) part |= __shfl_xor(part, s);
      remv |= part;
    }
  }
}

// ---------------- K7: masked-max IoU loss partials ----------------
__global__ __launch_bounds__(256) void k_loss(const float* __restrict__ boxesK,
                                              const int* __restrict__ clsK,
                                              const unsigned long long* __restrict__ keepw,
                                              float* __restrict__ part) {
#pragma clang fp contract(off)
  const int img = blockIdx.y;
  const int chunk = blockIdx.x;
  const int tp = 8 + img;
  __shared__ float px1[KMAX], py1[KMAX], px2[KMAX], py2[KMAX], pa[KMAX];
  __shared__ int pcls[KMAX];
  __shared__ float red[256];
  for (int j = threadIdx.x; j < KMAX; j += 256) {
    const float* bo = boxesK + ((size_t)tp * KMAX + j) * 4;
    float x1 = bo[0] / 640.0f, y1 = bo[1] / 640.0f;
    float x2 = bo[2] / 640.0f, y2 = bo[3] / 640.0f;
    px1[j] = x1; py1[j] = y1; px2[j] = x2; py2[j] = y2;
    pa[j] = (x2 - x1) * (y2 - y1);
    int kept = (int)((keepw[tp * 16 + (j >> 6)] >> (j & 63)) & 1ull);
    pcls[j] = kept ? clsK[tp * KMAX + j] : -1;
  }
  __syncthreads();
  const int row = chunk * 64 + (threadIdx.x & 63);
  const int stripe = threadIdx.x >> 6;
  const int ck = (int)((keepw[img * 16 + (row >> 6)] >> (row & 63)) & 1ull);
  const float* bo = boxesK + ((size_t)img * KMAX + row) * 4;
  float cx1 = bo[0] / 640.0f, cy1 = bo[1] / 640.0f;
  float cx2 = bo[2] / 640.0f, cy2 = bo[3] / 640.0f;
  float ca = (cx2 - cx1) * (cy2 - cy1);
  const int ccls = clsK[img * KMAX + row];
  float m = 0.0f;
  if (ck) {
    const int j0 = stripe * 256;
    for (int j = j0; j < j0 + 256; ++j) {
      if (pcls[j] == ccls) {
        float tlx = fmaxf(cx1, px1[j]);
        float tly = fmaxf(cy1, py1[j]);
        float brx = fminf(cx2, px2[j]);
        float bry = fminf(cy2, py2[j]);
        float w = fmaxf(brx - tlx, 0.0f);
        float h = fmaxf(bry - tly, 0.0f);
        float inter = w * h;
        float uni = (ca + pa[j]) - inter;
        uni = (uni > 0.0f) ? uni : 1.0f;
        m = fmaxf(m, inter / uni);
      }
    }
  }
  red[threadIdx.x] = m;
  __syncthreads();
  if (threadIdx.x < 64) {
    float mm = fmaxf(fmaxf(red[threadIdx.x], red[threadIdx.x + 64]),
                     fmaxf(red[threadIdx.x + 128], red[threadIdx.x + 192]));
    float sv = ck ? mm : 0.0f;
    float nv = ck ? 1.0f : 0.0f;
    for (int off = 32; off > 0; off >>= 1) {
      sv += __shfl_down(sv, off);
      nv += __shfl_down(nv, off);
    }
    if (threadIdx.x == 0) {
      int b = img * 8 + chunk;
      part[b * 2 + 0] = sv;
      part[b * 2 + 1] = nv;
    }
  }
}

// ---------------- K8: deterministic final reduce ----------------
__global__ __launch_bounds__(64) void k_final(const float* __restrict__ part,
                                              float* __restrict__ out) {
  int lane = threadIdx.x;
  float sv = part[lane * 2 + 0];
  float nv = part[lane * 2 + 1];
  for (int off = 32; off > 0; off >>= 1) {
    sv += __shfl_down(sv, off);
    nv += __shfl_down(nv, off);
  }
  if (lane == 0) out[0] = (nv > 0.0f) ? (1.0f - sv / fmaxf(nv, 1.0f)) : 1.0f;
}

extern "C" void kernel_launch(void* const* d_in, const int* in_sizes, int n_in,
                              void* d_out, int out_size, void* d_ws, size_t ws_size,
                              hipStream_t stream) {
  const float* clean = (const float*)d_in[0];
  const float* patch = (const float*)d_in[1];
  char* ws = (char*)d_ws;
  unsigned* keys            = (unsigned*)(ws + OFF_KEYS);
  int* clsArr               = (int*)(ws + OFF_CLS);
  float* boxesK             = (float*)(ws + OFF_BOX);
  int* clsK                 = (int*)(ws + OFF_CLSK);
  int* validK               = (int*)(ws + OFF_VALK);
  unsigned long long* keepw = (unsigned long long*)(ws + OFF_KEEP);
  unsigned long long* sup   = (unsigned long long*)(ws + OFF_SUP);
  unsigned long long* diag  = (unsigned long long*)(ws + OFF_DIAG);
  float* part               = (float*)(ws + OFF_PART);
  unsigned* hist            = (unsigned*)(ws + OFF_HIST);
  unsigned* cnt             = (unsigned*)(ws + OFF_CNT);
  unsigned* thr             = (unsigned*)(ws + OFF_THR);
  unsigned long long* cand  = (unsigned long long*)(ws + OFF_CAND);
  float* out                = (float*)d_out;

  k_zero   <<<256, 256, 0, stream>>>((uint4*)hist, cnt);
  k_score  <<<dim3((NA + 63) / 64, NT), 256, 0, stream>>>(clean, patch, keys, clsArr, hist);
  k_select <<<NT, 256, 0, stream>>>(hist, thr);
  k_compact<<<dim3((NA + 255) / 256, NT), 256, 0, stream>>>(keys, thr, cnt, cand);
  k_sort   <<<NT, 512, 0, stream>>>(clean, patch, cnt, cand, clsArr, boxesK, clsK, validK);
  k_ioumat <<<dim3(16, NT), 256, 0, stream>>>(boxesK, clsK, sup, diag);
  k_greedy <<<NT, 64, 0, stream>>>(sup, diag, validK, keepw);
  k_loss   <<<dim3(8, NB), 256, 0, stream>>>(boxesK, clsK, keepw, part);
  k_final  <<<1, 64, 0, stream>>>(part, out);
}

// Round 5
// 340.173 us; speedup vs baseline: 1.8591x; 1.2198x over previous
//
#include <hip/hip_runtime.h>

// Pipeline: k_score -> k_histsel (LDS hist + select, zeros cnt) -> k_compact
//           -> k_sort -> k_ioumat(+diag) -> k_greedy -> k_loss -> k_final

static constexpr int NB   = 8;
static constexpr int NA   = 25200;
static constexpr int NCLS = 80;
static constexpr int CH   = 85;
static constexpr int NT   = 16;    // 8 clean + 8 patch tasks
static constexpr int KMAX = 1024;
static constexpr int NBIN = 32768; // 15-bit prefix bins
static constexpr int PSH  = 17;    // key >> PSH = bin
static constexpr int CAP  = 2048;  // candidate buffer per task (hi[0,1024) eq[1024,2048))
static constexpr int CPAD = 32;    // counter padding (u32) -> one 128B line each

// workspace byte offsets (all 16B aligned)
static constexpr size_t OFF_KEYS = 0;                                     // 1,612,800
static constexpr size_t OFF_CLS  = OFF_KEYS + (size_t)NT * NA * 4;        // 1,612,800
static constexpr size_t OFF_BOX  = OFF_CLS  + (size_t)NT * NA * 4;        // 262,144
static constexpr size_t OFF_CLSK = OFF_BOX  + (size_t)NT * KMAX * 16;     // 65,536
static constexpr size_t OFF_VALK = OFF_CLSK + (size_t)NT * KMAX * 4;      // 65,536
static constexpr size_t OFF_KEEP = OFF_VALK + (size_t)NT * KMAX * 4;      // 2,048
static constexpr size_t OFF_SUP  = OFF_KEEP + (size_t)NT * 16 * 8;        // 2,097,152
static constexpr size_t OFF_DIAG = OFF_SUP  + (size_t)NT * KMAX * 16 * 8; // 131,072
static constexpr size_t OFF_PART = OFF_DIAG + (size_t)NT * KMAX * 8;      // 512
static constexpr size_t OFF_CNT  = OFF_PART + 512;                        // 4,096
static constexpr size_t OFF_THR  = OFF_CNT  + (size_t)NT * 2 * CPAD * 4;  // 128
static constexpr size_t OFF_CAND = OFF_THR  + 128;                        // 262,144
// total ~6.1 MB

__device__ __forceinline__ unsigned okey(float f) {
  unsigned u = __float_as_uint(f);
  return (u & 0x80000000u) ? ~u : (u | 0x80000000u);
}

// ---------------- K1: per-anchor score/class (pure streaming, NO atomics) ----------------
// 64 anchors / block, 4 threads per anchor.
__global__ __launch_bounds__(256) void k_score(const float* __restrict__ clean,
                                               const float* __restrict__ patch,
                                               unsigned* __restrict__ keys,
                                               int* __restrict__ clsArr) {
#pragma clang fp contract(off)
  const int t  = blockIdx.y;
  const int a0 = blockIdx.x * 64;
  const int nA = (NA - a0 < 64) ? (NA - a0) : 64;
  const float conf_th = (t < 8) ? 0.25f : 0.001f;
  const float* __restrict__ src = ((t < 8) ? clean : patch) + (size_t)(t & 7) * NA * CH;
  __shared__ float rows[64 * CH];
  const float4* g4 = (const float4*)(src + (size_t)a0 * CH);
  float4* s4 = (float4*)rows;
  const int n4 = (nA * CH) >> 2;
  for (int i = threadIdx.x; i < n4; i += 256) s4[i] = g4[i];
  __syncthreads();

  const int ar = threadIdx.x >> 2;  // anchor within tile
  const int q  = threadIdx.x & 3;   // class stripe
  if (ar < nA) {
    const float* r = rows + ar * CH;
    const float obj = r[4];
    const int c0 = q * 20;
    float best = r[5 + c0] * obj;  // products first (matches ref argmax over cls_conf)
    int bc = c0;
    for (int c = c0 + 1; c < c0 + 20; ++c) {
      float v = r[5 + c] * obj;
      if (v > best) { best = v; bc = c; }
    }
    {
      float b2 = __shfl_down(best, 2); int c2 = __shfl_down(bc, 2);
      if (b2 > best || (b2 == best && c2 < bc)) { best = b2; bc = c2; }
      float b1 = __shfl_down(best, 1); int c1 = __shfl_down(bc, 1);
      if (b1 > best || (b1 == best && c1 < bc)) { best = b1; bc = c1; }
    }
    if (q == 0) {
      const bool valid = (obj > conf_th) && (best > conf_th);
      const float score = valid ? best : -1e30f;
      const int a = a0 + ar;
      keys[(size_t)t * NA + a]   = okey(score);
      clsArr[(size_t)t * NA + a] = bc;
    }
  }
}

// ---------------- K2: per-task LDS histogram + fused threshold select ----------------
// one block per task; also zeroes this task's compact counters.
__global__ __launch_bounds__(1024) void k_histsel(const unsigned* __restrict__ keys,
                                                  unsigned* __restrict__ thr,
                                                  unsigned* __restrict__ cnt) {
  const int t = blockIdx.x;
  const unsigned K = (t < 8) ? 512u : 1024u;
  __shared__ unsigned h32[NBIN / 2];   // two 16-bit bins per word (64 KB)
  __shared__ unsigned csum[1024];      // chunk sums (32 bins / chunk)
  __shared__ int s_chunk;
  __shared__ unsigned s_acc;
  const int tid = threadIdx.x;
  for (int i = tid; i < NBIN / 2; i += 1024) h32[i] = 0u;
  if (tid < 2) cnt[(t * 2 + tid) * CPAD] = 0u;
  __syncthreads();
  const unsigned INVKEY = okey(-1e30f);
  const unsigned* kv = keys + (size_t)t * NA;
  const int lane = tid & 63;
  for (int i = tid; i < NA; i += 1024) {
    unsigned key = kv[i];
    bool inv = (key == INVKEY);
    unsigned long long mb = __ballot(inv);
    if (!inv) {
      unsigned b = key >> PSH;
      atomicAdd(&h32[b >> 1], 1u << ((b & 1) * 16));
    } else if (lane == (int)__ffsll(mb) - 1) {
      unsigned b = INVKEY >> PSH;
      atomicAdd(&h32[b >> 1], (unsigned)__popcll(mb) << ((b & 1) * 16));
    }
  }
  __syncthreads();
  // chunk sums: thread tid sums bins [tid*32, tid*32+32) = words [tid*16, tid*16+16)
  {
    unsigned sum = 0;
    for (int i = 0; i < 16; ++i) {
      unsigned v = h32[tid * 16 + i];
      sum += (v & 0xFFFFu) + (v >> 16);
    }
    csum[tid] = sum;
  }
  __syncthreads();
  // inclusive suffix scan over 1024 chunks
  for (int off = 1; off < 1024; off <<= 1) {
    unsigned v = csum[tid];
    if (tid + off < 1024) v += csum[tid + off];
    __syncthreads();
    csum[tid] = v;
    __syncthreads();
  }
  {
    bool pred = csum[tid] >= K;
    bool next = (tid == 1023) ? false : (csum[tid + 1] >= K);
    if (pred && !next) {
      s_chunk = tid;
      s_acc = (tid == 1023) ? 0u : csum[tid + 1];
    }
  }
  __syncthreads();
  if (tid == 0) {
    unsigned acc = s_acc;
    unsigned res = (unsigned)(s_chunk * 32);
    for (int i = 31; i >= 0; --i) {
      int bb = s_chunk * 32 + i;
      unsigned v = h32[bb >> 1];
      unsigned c2 = (bb & 1) ? (v >> 16) : (v & 0xFFFFu);
      if (acc + c2 >= K) { res = (unsigned)bb; break; }
      acc += c2;
    }
    thr[t] = res;
  }
}

// ---------------- K3: compact candidates (wave-aggregated atomics) ----------------
__global__ __launch_bounds__(256) void k_compact(const unsigned* __restrict__ keys,
                                                 const unsigned* __restrict__ thr,
                                                 unsigned* __restrict__ cnt,
                                                 unsigned long long* __restrict__ cand) {
  const int t = blockIdx.y;
  const int a = blockIdx.x * 256 + threadIdx.x;
  const unsigned B = thr[t];
  unsigned key = 0u, p = 0u;
  const bool inb = (a < NA);
  if (inb) { key = keys[(size_t)t * NA + a]; p = key >> PSH; }
  const bool hi = inb && (p > B);
  const bool eq = inb && (p == B);
  const unsigned long long item =
      ((unsigned long long)key << 32) | (unsigned)(~(unsigned)a);
  const int lane = threadIdx.x & 63;
  const unsigned long long lowmask =
      (lane == 0) ? 0ull : (0xFFFFFFFFFFFFFFFFull >> (64 - lane));
  unsigned long long mh = __ballot(hi);
  if (mh) {
    const int leader = (int)__ffsll(mh) - 1;
    unsigned base = 0;
    if (lane == leader) base = atomicAdd(&cnt[(t * 2 + 0) * CPAD], (unsigned)__popcll(mh));
    base = __shfl(base, leader);
    if (hi) {
      unsigned pos = base + (unsigned)__popcll(mh & lowmask);
      if (pos < 1024u) cand[(size_t)t * CAP + pos] = item;
    }
  }
  unsigned long long me = __ballot(eq);
  if (me) {
    const int leader = (int)__ffsll(me) - 1;
    unsigned base = 0;
    if (lane == leader) base = atomicAdd(&cnt[(t * 2 + 1) * CPAD], (unsigned)__popcll(me));
    base = __shfl(base, leader);
    if (eq) {
      unsigned pos = base + (unsigned)__popcll(me & lowmask);
      if (pos < 1024u) cand[(size_t)t * CAP + 1024 + pos] = item;
    }
  }
}

// ---------------- K4: bitonic sort candidates + gather top-K ----------------
__global__ __launch_bounds__(1024) void k_sort(const float* __restrict__ clean,
                                               const float* __restrict__ patch,
                                               const unsigned* __restrict__ cnt,
                                               const unsigned long long* __restrict__ cand,
                                               const int* __restrict__ clsArr,
                                               float* __restrict__ boxesK,
                                               int* __restrict__ clsK,
                                               int* __restrict__ validK) {
#pragma clang fp contract(off)
  const int t = blockIdx.x;
  const int K = (t < 8) ? 512 : 1024;
  const float conf_th = (t < 8) ? 0.25f : 0.001f;
  __shared__ unsigned long long buf[CAP];
  const unsigned nHi = min(cnt[(t * 2 + 0) * CPAD], 1024u);
  const unsigned nEq = min(cnt[(t * 2 + 1) * CPAD], 1024u);
  const unsigned long long* cd = cand + (size_t)t * CAP;
  for (int i = threadIdx.x; i < CAP; i += 1024) {
    unsigned long long v = 0ull;
    if (i < 1024) { if ((unsigned)i < nHi) v = cd[i]; }
    else          { if ((unsigned)(i - 1024) < nEq) v = cd[i]; }
    buf[i] = v;
  }
  __syncthreads();
  // bitonic sort descending; equal keys -> larger ~idx (= smaller idx) first
  for (int kk2 = 2; kk2 <= CAP; kk2 <<= 1) {
    for (int j = kk2 >> 1; j > 0; j >>= 1) {
      for (int i = threadIdx.x; i < CAP; i += 1024) {
        int ixj = i ^ j;
        if (ixj > i) {
          unsigned long long a = buf[i], b = buf[ixj];
          bool desc = ((i & kk2) == 0);
          if (desc ? (a < b) : (a > b)) { buf[i] = b; buf[ixj] = a; }
        }
      }
      __syncthreads();
    }
  }
  const float* __restrict__ src = ((t < 8) ? clean : patch) + (size_t)(t & 7) * NA * CH;
  const unsigned vkey = okey(conf_th);
  for (int k = threadIdx.x; k < K; k += 1024) {
    unsigned long long v = buf[k];
    unsigned key = (unsigned)(v >> 32);
    int idx = (int)(~(unsigned)(v & 0xFFFFFFFFull));
    if (idx < 0) idx = 0;  // padding entries (key 0) are masked downstream
    const float* r = src + (size_t)idx * CH;
    float cx = r[0], cy = r[1], w = r[2], h = r[3];
    float hw = w * 0.5f, hh = h * 0.5f;
    float* bo = boxesK + ((size_t)t * KMAX + k) * 4;
    bo[0] = cx - hw; bo[1] = cy - hh; bo[2] = cx + hw; bo[3] = cy + hh;
    clsK[t * KMAX + k]   = clsArr[(size_t)t * NA + idx];
    validK[t * KMAX + k] = (key > vkey) ? 1 : 0;
  }
}

// ---------------- K5: suppression bit-matrix (upper triangle only) + diag ----------------
__global__ __launch_bounds__(256) void k_ioumat(const float* __restrict__ boxesK,
                                                const int* __restrict__ clsK,
                                                unsigned long long* __restrict__ sup,
                                                unsigned long long* __restrict__ diag) {
#pragma clang fp contract(off)
  const int t  = blockIdx.y;
  const int K  = (t < 8) ? 512 : 1024;
  const int lw = (t < 8) ? 3 : 4;
  const int nw = 1 << lw;
  __shared__ float X1[KMAX + 16], Y1[KMAX + 16], X2[KMAX + 16], Y2[KMAX + 16], AR[KMAX + 16];
  for (int i = threadIdx.x; i < K; i += 256) {
    const float* bo = boxesK + ((size_t)t * KMAX + i) * 4;
    float off = (float)clsK[t * KMAX + i] * 4096.0f;
    float x1 = bo[0] + off, y1 = bo[1] + off, x2 = bo[2] + off, y2 = bo[3] + off;
    const int ip = i + (i >> 6);
    X1[ip] = x1; Y1[ip] = y1; X2[ip] = x2; Y2[ip] = y2;
    AR[ip] = (x2 - x1) * (y2 - y1);
  }
  __syncthreads();
  const int total = K * nw;
  unsigned long long* supt = sup + (size_t)t * (KMAX * 16);
  for (int widx = blockIdx.x * 256 + threadIdx.x; widx < total; widx += 16 * 256) {
    int i  = widx >> lw;
    int wc = widx & (nw - 1);
    if (wc < (i >> 6)) continue;  // lower triangle never read
    const int ipi = i + (i >> 6);
    float x1i = X1[ipi], y1i = Y1[ipi], x2i = X2[ipi], y2i = Y2[ipi], ai = AR[ipi];
    unsigned long long m = 0ull;
    const int jb = (wc << 6) + wc;
    for (int l = 0; l < 64; ++l) {
      int j = (wc << 6) + l;
      if (j > i) {
        int jp = jb + l;
        float tlx = fmaxf(x1i, X1[jp]);
        float tly = fmaxf(y1i, Y1[jp]);
        float brx = fminf(x2i, X2[jp]);
        float bry = fminf(y2i, Y2[jp]);
        float w = fmaxf(brx - tlx, 0.0f);
        float h = fmaxf(bry - tly, 0.0f);
        float inter = w * h;
        float uni = (ai + AR[jp]) - inter;
        uni = (uni > 0.0f) ? uni : 1.0f;
        float iou = inter / uni;
        if (iou > 0.45f) m |= (1ull << l);
      }
    }
    supt[(size_t)i * nw + wc] = m;
    if (wc == (i >> 6)) diag[(size_t)t * KMAX + i] = m;
  }
}

// ---------------- K6: greedy NMS — LDS diag chain + sparse kept-row gather ----------------
__global__ __launch_bounds__(64) void k_greedy(const unsigned long long* __restrict__ sup,
                                               const unsigned long long* __restrict__ diag,
                                               const int* __restrict__ validK,
                                               unsigned long long* __restrict__ keepw) {
  const int t  = blockIdx.x;
  const int K  = (t < 8) ? 512 : 1024;
  const int lw = (t < 8) ? 3 : 4;
  const int nw = 1 << lw;
  const int lane = threadIdx.x;
  __shared__ unsigned long long sdiag[KMAX];
  const unsigned long long* dg = diag + (size_t)t * KMAX;
  for (int i = lane; i < K; i += 64) sdiag[i] = dg[i];
  int v16[16];
#pragma unroll
  for (int W = 0; W < 16; ++W)
    v16[W] = (W < nw) ? validK[t * KMAX + W * 64 + lane] : 0;
  unsigned long long vkeep = 0ull;
#pragma unroll
  for (int W = 0; W < 16; ++W)
    if (W < nw) {
      unsigned long long bl = __ballot(v16[W] != 0);
      if (lane == W) vkeep = bl;
    }
  __syncthreads();
  const int w = lane & (nw - 1);
  const int b = lane >> lw;
  const unsigned long long* base = sup + (size_t)t * (KMAX * 16);
  unsigned long long remv = 0ull;
  for (int W = 0; W < nw; ++W) {
    unsigned long long cur = __shfl(vkeep, W) & ~__shfl(remv, W);
    for (int rb = 0; rb < 64; rb += 16) {
      unsigned long long tm[16];
#pragma unroll
      for (int i2 = 0; i2 < 16; ++i2) tm[i2] = sdiag[W * 64 + rb + i2];
#pragma unroll
      for (int i2 = 0; i2 < 16; ++i2) {
        unsigned long long msk = 0ull - ((cur >> (rb + i2)) & 1ull);
        cur &= ~(tm[i2] & msk);
      }
    }
    if (lane == 0) keepw[t * 16 + W] = cur;
    if (W + 1 < nw) {
      const int r0 = b * nw;
      unsigned long long vv[16];
#pragma unroll
      for (int j = 0; j < 16; ++j) {
        bool take = (j < nw) && (w > W) && ((cur >> (r0 + j)) & 1ull);
        vv[j] = take ? base[(size_t)(W * 64 + r0 + j) * nw + w] : 0ull;
      }
      unsigned long long part = 0ull;
#pragma unroll
      for (int j = 0; j < 16; ++j) part |= vv[j];
      for (int s = nw; s < 64; s <<= 1) part |= __shfl_xor(part, s);
      remv |= part;
    }
  }
}

// ---------------- K7: masked-max IoU loss partials ----------------
__global__ __launch_bounds__(256) void k_loss(const float* __restrict__ boxesK,
                                              const int* __restrict__ clsK,
                                              const unsigned long long* __restrict__ keepw,
                                              float* __restrict__ part) {
#pragma clang fp contract(off)
  const int img = blockIdx.y;
  const int chunk = blockIdx.x;
  const int tp = 8 + img;
  __shared__ float px1[KMAX], py1[KMAX], px2[KMAX], py2[KMAX], pa[KMAX];
  __shared__ int pcls[KMAX];
  __shared__ float red[256];
  for (int j = threadIdx.x; j < KMAX; j += 256) {
    const float* bo = boxesK + ((size_t)tp * KMAX + j) * 4;
    float x1 = bo[0] / 640.0f, y1 = bo[1] / 640.0f;
    float x2 = bo[2] / 640.0f, y2 = bo[3] / 640.0f;
    px1[j] = x1; py1[j] = y1; px2[j] = x2; py2[j] = y2;
    pa[j] = (x2 - x1) * (y2 - y1);
    int kept = (int)((keepw[tp * 16 + (j >> 6)] >> (j & 63)) & 1ull);
    pcls[j] = kept ? clsK[tp * KMAX + j] : -1;
  }
  __syncthreads();
  const int row = chunk * 64 + (threadIdx.x & 63);
  const int stripe = threadIdx.x >> 6;
  const int ck = (int)((keepw[img * 16 + (row >> 6)] >> (row & 63)) & 1ull);
  const float* bo = boxesK + ((size_t)img * KMAX + row) * 4;
  float cx1 = bo[0] / 640.0f, cy1 = bo[1] / 640.0f;
  float cx2 = bo[2] / 640.0f, cy2 = bo[3] / 640.0f;
  float ca = (cx2 - cx1) * (cy2 - cy1);
  const int ccls = clsK[img * KMAX + row];
  float m = 0.0f;
  if (ck) {
    const int j0 = stripe * 256;
    for (int j = j0; j < j0 + 256; ++j) {
      if (pcls[j] == ccls) {
        float tlx = fmaxf(cx1, px1[j]);
        float tly = fmaxf(cy1, py1[j]);
        float brx = fminf(cx2, px2[j]);
        float bry = fminf(cy2, py2[j]);
        float w = fmaxf(brx - tlx, 0.0f);
        float h = fmaxf(bry - tly, 0.0f);
        float inter = w * h;
        float uni = (ca + pa[j]) - inter;
        uni = (uni > 0.0f) ? uni : 1.0f;
        m = fmaxf(m, inter / uni);
      }
    }
  }
  red[threadIdx.x] = m;
  __syncthreads();
  if (threadIdx.x < 64) {
    float mm = fmaxf(fmaxf(red[threadIdx.x], red[threadIdx.x + 64]),
                     fmaxf(red[threadIdx.x + 128], red[threadIdx.x + 192]));
    float sv = ck ? mm : 0.0f;
    float nv = ck ? 1.0f : 0.0f;
    for (int off = 32; off > 0; off >>= 1) {
      sv += __shfl_down(sv, off);
      nv += __shfl_down(nv, off);
    }
    if (threadIdx.x == 0) {
      int b = img * 8 + chunk;
      part[b * 2 + 0] = sv;
      part[b * 2 + 1] = nv;
    }
  }
}

// ---------------- K8: deterministic final reduce ----------------
__global__ __launch_bounds__(64) void k_final(const float* __restrict__ part,
                                              float* __restrict__ out) {
  int lane = threadIdx.x;
  float sv = part[lane * 2 + 0];
  float nv = part[lane * 2 + 1];
  for (int off = 32; off > 0; off >>= 1) {
    sv += __shfl_down(sv, off);
    nv += __shfl_down(nv, off);
  }
  if (lane == 0) out[0] = (nv > 0.0f) ? (1.0f - sv / fmaxf(nv, 1.0f)) : 1.0f;
}

extern "C" void kernel_launch(void* const* d_in, const int* in_sizes, int n_in,
                              void* d_out, int out_size, void* d_ws, size_t ws_size,
                              hipStream_t stream) {
  const float* clean = (const float*)d_in[0];
  const float* patch = (const float*)d_in[1];
  char* ws = (char*)d_ws;
  unsigned* keys            = (unsigned*)(ws + OFF_KEYS);
  int* clsArr               = (int*)(ws + OFF_CLS);
  float* boxesK             = (float*)(ws + OFF_BOX);
  int* clsK                 = (int*)(ws + OFF_CLSK);
  int* validK               = (int*)(ws + OFF_VALK);
  unsigned long long* keepw = (unsigned long long*)(ws + OFF_KEEP);
  unsigned long long* sup   = (unsigned long long*)(ws + OFF_SUP);
  unsigned long long* diag  = (unsigned long long*)(ws + OFF_DIAG);
  float* part               = (float*)(ws + OFF_PART);
  unsigned* cnt             = (unsigned*)(ws + OFF_CNT);
  unsigned* thr             = (unsigned*)(ws + OFF_THR);
  unsigned long long* cand  = (unsigned long long*)(ws + OFF_CAND);
  float* out                = (float*)d_out;

  k_score  <<<dim3((NA + 63) / 64, NT), 256, 0, stream>>>(clean, patch, keys, clsArr);
  k_histsel<<<NT, 1024, 0, stream>>>(keys, thr, cnt);
  k_compact<<<dim3((NA + 255) / 256, NT), 256, 0, stream>>>(keys, thr, cnt, cand);
  k_sort   <<<NT, 1024, 0, stream>>>(clean, patch, cnt, cand, clsArr, boxesK, clsK, validK);
  k_ioumat <<<dim3(16, NT), 256, 0, stream>>>(boxesK, clsK, sup, diag);
  k_greedy <<<NT, 64, 0, stream>>>(sup, diag, validK, keepw);
  k_loss   <<<dim3(8, NB), 256, 0, stream>>>(boxesK, clsK, keepw, part);
  k_final  <<<1, 64, 0, stream>>>(part, out);
}

// Round 6
// 277.972 us; speedup vs baseline: 2.2750x; 1.2238x over previous
//
#include <hip/hip_runtime.h>

// Pipeline: k_score -> k_histsel (LDS hist + select, zeros cnt) -> k_compact
//           -> k_sort -> k_ioumat(+diag, triangular) -> k_greedy -> k_loss -> k_final

static constexpr int NB   = 8;
static constexpr int NA   = 25200;
static constexpr int NCLS = 80;
static constexpr int CH   = 85;
static constexpr int NT   = 16;    // 8 clean + 8 patch tasks
static constexpr int KMAX = 1024;
static constexpr int NBIN = 32768; // 15-bit prefix bins
static constexpr int PSH  = 17;    // key >> PSH = bin
static constexpr int CAP  = 2048;  // candidate buffer per task (hi[0,1024) eq[1024,2048))
static constexpr int CPAD = 32;    // counter padding (u32) -> one 128B line each
static constexpr int IOB  = 34;    // x-blocks for k_ioumat (patch: 136 pairs*64 rows = 34*256)

// workspace byte offsets (all 16B aligned)
static constexpr size_t OFF_KEYS = 0;                                     // 1,612,800
static constexpr size_t OFF_CLS  = OFF_KEYS + (size_t)NT * NA * 4;        // 1,612,800
static constexpr size_t OFF_BOX  = OFF_CLS  + (size_t)NT * NA * 4;        // 262,144
static constexpr size_t OFF_CLSK = OFF_BOX  + (size_t)NT * KMAX * 16;     // 65,536
static constexpr size_t OFF_VALK = OFF_CLSK + (size_t)NT * KMAX * 4;      // 65,536
static constexpr size_t OFF_KEEP = OFF_VALK + (size_t)NT * KMAX * 4;      // 2,048
static constexpr size_t OFF_SUP  = OFF_KEEP + (size_t)NT * 16 * 8;        // 2,097,152
static constexpr size_t OFF_DIAG = OFF_SUP  + (size_t)NT * KMAX * 16 * 8; // 131,072
static constexpr size_t OFF_PART = OFF_DIAG + (size_t)NT * KMAX * 8;      // 512
static constexpr size_t OFF_CNT  = OFF_PART + 512;                        // 4,096
static constexpr size_t OFF_THR  = OFF_CNT  + (size_t)NT * 2 * CPAD * 4;  // 128
static constexpr size_t OFF_CAND = OFF_THR  + 128;                        // 262,144
// total ~6.1 MB

__device__ __forceinline__ unsigned okey(float f) {
  unsigned u = __float_as_uint(f);
  return (u & 0x80000000u) ? ~u : (u | 0x80000000u);
}

// ---------------- K1: per-anchor score/class (pure streaming, NO atomics) ----------------
__global__ __launch_bounds__(256) void k_score(const float* __restrict__ clean,
                                               const float* __restrict__ patch,
                                               unsigned* __restrict__ keys,
                                               int* __restrict__ clsArr) {
#pragma clang fp contract(off)
  const int t  = blockIdx.y;
  const int a0 = blockIdx.x * 64;
  const int nA = (NA - a0 < 64) ? (NA - a0) : 64;
  const float conf_th = (t < 8) ? 0.25f : 0.001f;
  const float* __restrict__ src = ((t < 8) ? clean : patch) + (size_t)(t & 7) * NA * CH;
  __shared__ float rows[64 * CH];
  const float4* g4 = (const float4*)(src + (size_t)a0 * CH);
  float4* s4 = (float4*)rows;
  const int n4 = (nA * CH) >> 2;
  for (int i = threadIdx.x; i < n4; i += 256) s4[i] = g4[i];
  __syncthreads();

  const int ar = threadIdx.x >> 2;
  const int q  = threadIdx.x & 3;
  if (ar < nA) {
    const float* r = rows + ar * CH;
    const float obj = r[4];
    const int c0 = q * 20;
    float best = r[5 + c0] * obj;  // products first (matches ref argmax over cls_conf)
    int bc = c0;
    for (int c = c0 + 1; c < c0 + 20; ++c) {
      float v = r[5 + c] * obj;
      if (v > best) { best = v; bc = c; }
    }
    {
      float b2 = __shfl_down(best, 2); int c2 = __shfl_down(bc, 2);
      if (b2 > best || (b2 == best && c2 < bc)) { best = b2; bc = c2; }
      float b1 = __shfl_down(best, 1); int c1 = __shfl_down(bc, 1);
      if (b1 > best || (b1 == best && c1 < bc)) { best = b1; bc = c1; }
    }
    if (q == 0) {
      const bool valid = (obj > conf_th) && (best > conf_th);
      const float score = valid ? best : -1e30f;
      const int a = a0 + ar;
      keys[(size_t)t * NA + a]   = okey(score);
      clsArr[(size_t)t * NA + a] = bc;
    }
  }
}

// ---------------- K2: per-task LDS histogram + fused threshold select ----------------
__global__ __launch_bounds__(1024) void k_histsel(const unsigned* __restrict__ keys,
                                                  unsigned* __restrict__ thr,
                                                  unsigned* __restrict__ cnt) {
  const int t = blockIdx.x;
  const unsigned K = (t < 8) ? 512u : 1024u;
  __shared__ unsigned h32[NBIN / 2];   // two 16-bit bins per word (64 KB)
  __shared__ unsigned csum[1024];
  __shared__ int s_chunk;
  __shared__ unsigned s_acc;
  const int tid = threadIdx.x;
  for (int i = tid; i < NBIN / 2; i += 1024) h32[i] = 0u;
  if (tid < 2) cnt[(t * 2 + tid) * CPAD] = 0u;
  __syncthreads();
  const unsigned INVKEY = okey(-1e30f);
  const unsigned* kv = keys + (size_t)t * NA;
  const int lane = tid & 63;
  for (int i = tid; i < NA; i += 1024) {
    unsigned key = kv[i];
    bool inv = (key == INVKEY);
    unsigned long long mb = __ballot(inv);
    if (!inv) {
      unsigned b = key >> PSH;
      atomicAdd(&h32[b >> 1], 1u << ((b & 1) * 16));
    } else if (lane == (int)__ffsll(mb) - 1) {
      unsigned b = INVKEY >> PSH;
      atomicAdd(&h32[b >> 1], (unsigned)__popcll(mb) << ((b & 1) * 16));
    }
  }
  __syncthreads();
  {
    unsigned sum = 0;
    for (int i = 0; i < 16; ++i) {
      unsigned v = h32[tid * 16 + i];
      sum += (v & 0xFFFFu) + (v >> 16);
    }
    csum[tid] = sum;
  }
  __syncthreads();
  for (int off = 1; off < 1024; off <<= 1) {
    unsigned v = csum[tid];
    if (tid + off < 1024) v += csum[tid + off];
    __syncthreads();
    csum[tid] = v;
    __syncthreads();
  }
  {
    bool pred = csum[tid] >= K;
    bool next = (tid == 1023) ? false : (csum[tid + 1] >= K);
    if (pred && !next) {
      s_chunk = tid;
      s_acc = (tid == 1023) ? 0u : csum[tid + 1];
    }
  }
  __syncthreads();
  if (tid == 0) {
    unsigned acc = s_acc;
    unsigned res = (unsigned)(s_chunk * 32);
    for (int i = 31; i >= 0; --i) {
      int bb = s_chunk * 32 + i;
      unsigned v = h32[bb >> 1];
      unsigned c2 = (bb & 1) ? (v >> 16) : (v & 0xFFFFu);
      if (acc + c2 >= K) { res = (unsigned)bb; break; }
      acc += c2;
    }
    thr[t] = res;
  }
}

// ---------------- K3: compact candidates (wave-aggregated atomics) ----------------
__global__ __launch_bounds__(256) void k_compact(const unsigned* __restrict__ keys,
                                                 const unsigned* __restrict__ thr,
                                                 unsigned* __restrict__ cnt,
                                                 unsigned long long* __restrict__ cand) {
  const int t = blockIdx.y;
  const int a = blockIdx.x * 256 + threadIdx.x;
  const unsigned B = thr[t];
  unsigned key = 0u, p = 0u;
  const bool inb = (a < NA);
  if (inb) { key = keys[(size_t)t * NA + a]; p = key >> PSH; }
  const bool hi = inb && (p > B);
  const bool eq = inb && (p == B);
  const unsigned long long item =
      ((unsigned long long)key << 32) | (unsigned)(~(unsigned)a);
  const int lane = threadIdx.x & 63;
  const unsigned long long lowmask =
      (lane == 0) ? 0ull : (0xFFFFFFFFFFFFFFFFull >> (64 - lane));
  unsigned long long mh = __ballot(hi);
  if (mh) {
    const int leader = (int)__ffsll(mh) - 1;
    unsigned base = 0;
    if (lane == leader) base = atomicAdd(&cnt[(t * 2 + 0) * CPAD], (unsigned)__popcll(mh));
    base = __shfl(base, leader);
    if (hi) {
      unsigned pos = base + (unsigned)__popcll(mh & lowmask);
      if (pos < 1024u) cand[(size_t)t * CAP + pos] = item;
    }
  }
  unsigned long long me = __ballot(eq);
  if (me) {
    const int leader = (int)__ffsll(me) - 1;
    unsigned base = 0;
    if (lane == leader) base = atomicAdd(&cnt[(t * 2 + 1) * CPAD], (unsigned)__popcll(me));
    base = __shfl(base, leader);
    if (eq) {
      unsigned pos = base + (unsigned)__popcll(me & lowmask);
      if (pos < 1024u) cand[(size_t)t * CAP + 1024 + pos] = item;
    }
  }
}

// ---------------- K4: bitonic sort candidates + gather top-K ----------------
__global__ __launch_bounds__(1024) void k_sort(const float* __restrict__ clean,
                                               const float* __restrict__ patch,
                                               const unsigned* __restrict__ cnt,
                                               const unsigned long long* __restrict__ cand,
                                               const int* __restrict__ clsArr,
                                               float* __restrict__ boxesK,
                                               int* __restrict__ clsK,
                                               int* __restrict__ validK) {
#pragma clang fp contract(off)
  const int t = blockIdx.x;
  const int K = (t < 8) ? 512 : 1024;
  const float conf_th = (t < 8) ? 0.25f : 0.001f;
  __shared__ unsigned long long buf[CAP];
  const unsigned nHi = min(cnt[(t * 2 + 0) * CPAD], 1024u);
  const unsigned nEq = min(cnt[(t * 2 + 1) * CPAD], 1024u);
  const unsigned long long* cd = cand + (size_t)t * CAP;
  for (int i = threadIdx.x; i < CAP; i += 1024) {
    unsigned long long v = 0ull;
    if (i < 1024) { if ((unsigned)i < nHi) v = cd[i]; }
    else          { if ((unsigned)(i - 1024) < nEq) v = cd[i]; }
    buf[i] = v;
  }
  __syncthreads();
  for (int kk2 = 2; kk2 <= CAP; kk2 <<= 1) {
    for (int j = kk2 >> 1; j > 0; j >>= 1) {
      for (int i = threadIdx.x; i < CAP; i += 1024) {
        int ixj = i ^ j;
        if (ixj > i) {
          unsigned long long a = buf[i], b = buf[ixj];
          bool desc = ((i & kk2) == 0);
          if (desc ? (a < b) : (a > b)) { buf[i] = b; buf[ixj] = a; }
        }
      }
      __syncthreads();
    }
  }
  const float* __restrict__ src = ((t < 8) ? clean : patch) + (size_t)(t & 7) * NA * CH;
  const unsigned vkey = okey(conf_th);
  for (int k = threadIdx.x; k < K; k += 1024) {
    unsigned long long v = buf[k];
    unsigned key = (unsigned)(v >> 32);
    int idx = (int)(~(unsigned)(v & 0xFFFFFFFFull));
    if (idx < 0) idx = 0;  // padding entries (key 0) are masked downstream
    const float* r = src + (size_t)idx * CH;
    float cx = r[0], cy = r[1], w = r[2], h = r[3];
    float hw = w * 0.5f, hh = h * 0.5f;
    float* bo = boxesK + ((size_t)t * KMAX + k) * 4;
    bo[0] = cx - hw; bo[1] = cy - hh; bo[2] = cx + hw; bo[3] = cy + hh;
    clsK[t * KMAX + k]   = clsArr[(size_t)t * NA + idx];
    validK[t * KMAX + k] = (key > vkey) ? 1 : 0;
  }
}

// ---------------- K5: suppression bit-matrix, triangular enumeration ----------------
// pair p=(rb,wc), wc>=rb; widx = p*64 + row; lanes = 64 consecutive rows ->
// j-side LDS reads are wave-uniform broadcasts; off-diagonal body branchless.
__global__ __launch_bounds__(256) void k_ioumat(const float* __restrict__ boxesK,
                                                const int* __restrict__ clsK,
                                                unsigned long long* __restrict__ sup,
                                                unsigned long long* __restrict__ diag) {
#pragma clang fp contract(off)
  const int t  = blockIdx.y;
  const int K  = (t < 8) ? 512 : 1024;
  const int lw = (t < 8) ? 3 : 4;
  const int nw = 1 << lw;
  const int npair = (nw * (nw + 1)) / 2;
  const int total = npair * 64;
  if (blockIdx.x * 256 >= total) return;  // clean tasks use only 9 of 34 x-blocks
  __shared__ float X1[KMAX + 16], Y1[KMAX + 16], X2[KMAX + 16], Y2[KMAX + 16], AR[KMAX + 16];
  for (int i = threadIdx.x; i < K; i += 256) {
    const float* bo = boxesK + ((size_t)t * KMAX + i) * 4;
    float off = (float)clsK[t * KMAX + i] * 4096.0f;
    float x1 = bo[0] + off, y1 = bo[1] + off, x2 = bo[2] + off, y2 = bo[3] + off;
    const int ip = i + (i >> 6);
    X1[ip] = x1; Y1[ip] = y1; X2[ip] = x2; Y2[ip] = y2;
    AR[ip] = (x2 - x1) * (y2 - y1);
  }
  __syncthreads();
  unsigned long long* supt = sup + (size_t)t * (KMAX * 16);
  for (int widx = blockIdx.x * 256 + threadIdx.x; widx < total; widx += IOB * 256) {
    int p = widx >> 6;       // pair index (wave-uniform)
    int row = widx & 63;     // lane = row within block
    int rb = 0, pr = p;
    while (pr >= nw - rb) { pr -= nw - rb; ++rb; }
    const int wc = rb + pr;
    const int i = rb * 64 + row;
    const int ipi = i + rb;
    const float x1i = X1[ipi], y1i = Y1[ipi], x2i = X2[ipi], y2i = Y2[ipi], ai = AR[ipi];
    unsigned long long m = 0ull;
    const int jb = (wc << 6) + wc;  // padded base for j = wc*64 + l
    const bool offd = (wc > rb);
#pragma unroll 4
    for (int l = 0; l < 64; ++l) {
      const int jp = jb + l;                    // wave-uniform -> LDS broadcast
      float tlx = fmaxf(x1i, X1[jp]);
      float tly = fmaxf(y1i, Y1[jp]);
      float brx = fminf(x2i, X2[jp]);
      float bry = fminf(y2i, Y2[jp]);
      float w = fmaxf(brx - tlx, 0.0f);
      float h = fmaxf(bry - tly, 0.0f);
      float inter = w * h;
      float uni = (ai + AR[jp]) - inter;
      uni = (uni > 0.0f) ? uni : 1.0f;
      float iou = inter / uni;                  // IEEE div, bit-matches ref compare
      bool hit = (iou > 0.45f) && (offd || ((wc << 6) + l > i));
      m |= hit ? (1ull << l) : 0ull;
    }
    supt[(size_t)i * nw + wc] = m;
    if (wc == rb) diag[(size_t)t * KMAX + i] = m;
  }
}

// ---------------- K6: greedy NMS — LDS diag chain + sparse kept-row gather ----------------
__global__ __launch_bounds__(64) void k_greedy(const unsigned long long* __restrict__ sup,
                                               const unsigned long long* __restrict__ diag,
                                               const int* __restrict__ validK,
                                               unsigned long long* __restrict__ keepw) {
  const int t  = blockIdx.x;
  const int K  = (t < 8) ? 512 : 1024;
  const int lw = (t < 8) ? 3 : 4;
  const int nw = 1 << lw;
  const int lane = threadIdx.x;
  __shared__ unsigned long long sdiag[KMAX];
  const unsigned long long* dg = diag + (size_t)t * KMAX;
  for (int i = lane; i < K; i += 64) sdiag[i] = dg[i];
  int v16[16];
#pragma unroll
  for (int W = 0; W < 16; ++W)
    v16[W] = (W < nw) ? validK[t * KMAX + W * 64 + lane] : 0;
  unsigned long long vkeep = 0ull;
#pragma unroll
  for (int W = 0; W < 16; ++W)
    if (W < nw) {
      unsigned long long bl = __ballot(v16[W] != 0);
      if (lane == W) vkeep = bl;
    }
  __syncthreads();
  const int w = lane & (nw - 1);
  const int b = lane >> lw;
  const unsigned long long* base = sup + (size_t)t * (KMAX * 16);
  unsigned long long remv = 0ull;
  for (int W = 0; W < nw; ++W) {
    unsigned long long cur = __shfl(vkeep, W) & ~__shfl(remv, W);
    for (int rb = 0; rb < 64; rb += 16) {
      unsigned long long tm[16];
#pragma unroll
      for (int i2 = 0; i2 < 16; ++i2) tm[i2] = sdiag[W * 64 + rb + i2];
#pragma unroll
      for (int i2 = 0; i2 < 16; ++i2) {
        unsigned long long msk = 0ull - ((cur >> (rb + i2)) & 1ull);
        cur &= ~(tm[i2] & msk);
      }
    }
    if (lane == 0) keepw[t * 16 + W] = cur;
    if (W + 1 < nw) {
      const int r0 = b * nw;
      unsigned long long vv[16];
#pragma unroll
      for (int j = 0; j < 16; ++j) {
        bool take = (j < nw) && (w > W) && ((cur >> (r0 + j)) & 1ull);
        vv[j] = take ? base[(size_t)(W * 64 + r0 + j) * nw + w] : 0ull;
      }
      unsigned long long part = 0ull;
#pragma unroll
      for (int j = 0; j < 16; ++j) part |= vv[j];
      for (int s = nw; s < 64; s <<= 1) part |= __shfl_xor(part, s);
      remv |= part;
    }
  }
}

// ---------------- K7: masked-max IoU loss partials (1024 thr, 16 stripes) ----------------
__global__ __launch_bounds__(1024) void k_loss(const float* __restrict__ boxesK,
                                               const int* __restrict__ clsK,
                                               const unsigned long long* __restrict__ keepw,
                                               float* __restrict__ part) {
#pragma clang fp contract(off)
  const int img = blockIdx.y;
  const int chunk = blockIdx.x;
  const int tp = 8 + img;
  __shared__ float px1[KMAX], py1[KMAX], px2[KMAX], py2[KMAX], pa[KMAX];
  __shared__ int pcls[KMAX];
  __shared__ float red[1024];
  for (int j = threadIdx.x; j < KMAX; j += 1024) {
    const float* bo = boxesK + ((size_t)tp * KMAX + j) * 4;
    float x1 = bo[0] / 640.0f, y1 = bo[1] / 640.0f;
    float x2 = bo[2] / 640.0f, y2 = bo[3] / 640.0f;
    px1[j] = x1; py1[j] = y1; px2[j] = x2; py2[j] = y2;
    pa[j] = (x2 - x1) * (y2 - y1);
    int kept = (int)((keepw[tp * 16 + (j >> 6)] >> (j & 63)) & 1ull);
    pcls[j] = kept ? clsK[tp * KMAX + j] : -1;
  }
  __syncthreads();
  const int row = chunk * 64 + (threadIdx.x & 63);
  const int stripe = threadIdx.x >> 6;          // 0..15
  const int ck = (int)((keepw[img * 16 + (row >> 6)] >> (row & 63)) & 1ull);
  const float* bo = boxesK + ((size_t)img * KMAX + row) * 4;
  float cx1 = bo[0] / 640.0f, cy1 = bo[1] / 640.0f;
  float cx2 = bo[2] / 640.0f, cy2 = bo[3] / 640.0f;
  float ca = (cx2 - cx1) * (cy2 - cy1);
  const int ccls = clsK[img * KMAX + row];
  float m = 0.0f;
  if (ck) {
    const int j0 = stripe * 64;
    for (int j = j0; j < j0 + 64; ++j) {
      if (pcls[j] == ccls) {
        float tlx = fmaxf(cx1, px1[j]);
        float tly = fmaxf(cy1, py1[j]);
        float brx = fminf(cx2, px2[j]);
        float bry = fminf(cy2, py2[j]);
        float w = fmaxf(brx - tlx, 0.0f);
        float h = fmaxf(bry - tly, 0.0f);
        float inter = w * h;
        float uni = (ca + pa[j]) - inter;
        uni = (uni > 0.0f) ? uni : 1.0f;
        m = fmaxf(m, inter / uni);
      }
    }
  }
  red[threadIdx.x] = m;
  __syncthreads();
  if (threadIdx.x < 64) {
    float mm = red[threadIdx.x];
#pragma unroll
    for (int s = 1; s < 16; ++s) mm = fmaxf(mm, red[threadIdx.x + 64 * s]);
    float sv = ck ? mm : 0.0f;
    float nv = ck ? 1.0f : 0.0f;
    for (int off = 32; off > 0; off >>= 1) {
      sv += __shfl_down(sv, off);
      nv += __shfl_down(nv, off);
    }
    if (threadIdx.x == 0) {
      int b = img * 8 + chunk;
      part[b * 2 + 0] = sv;
      part[b * 2 + 1] = nv;
    }
  }
}

// ---------------- K8: deterministic final reduce ----------------
__global__ __launch_bounds__(64) void k_final(const float* __restrict__ part,
                                              float* __restrict__ out) {
  int lane = threadIdx.x;
  float sv = part[lane * 2 + 0];
  float nv = part[lane * 2 + 1];
  for (int off = 32; off > 0; off >>= 1) {
    sv += __shfl_down(sv, off);
    nv += __shfl_down(nv, off);
  }
  if (lane == 0) out[0] = (nv > 0.0f) ? (1.0f - sv / fmaxf(nv, 1.0f)) : 1.0f;
}

extern "C" void kernel_launch(void* const* d_in, const int* in_sizes, int n_in,
                              void* d_out, int out_size, void* d_ws, size_t ws_size,
                              hipStream_t stream) {
  const float* clean = (const float*)d_in[0];
  const float* patch = (const float*)d_in[1];
  char* ws = (char*)d_ws;
  unsigned* keys            = (unsigned*)(ws + OFF_KEYS);
  int* clsArr               = (int*)(ws + OFF_CLS);
  float* boxesK             = (float*)(ws + OFF_BOX);
  int* clsK                 = (int*)(ws + OFF_CLSK);
  int* validK               = (int*)(ws + OFF_VALK);
  unsigned long long* keepw = (unsigned long long*)(ws + OFF_KEEP);
  unsigned long long* sup   = (unsigned long long*)(ws + OFF_SUP);
  unsigned long long* diag  = (unsigned long long*)(ws + OFF_DIAG);
  float* part               = (float*)(ws + OFF_PART);
  unsigned* cnt             = (unsigned*)(ws + OFF_CNT);
  unsigned* thr             = (unsigned*)(ws + OFF_THR);
  unsigned long long* cand  = (unsigned long long*)(ws + OFF_CAND);
  float* out                = (float*)d_out;

  k_score  <<<dim3((NA + 63) / 64, NT), 256, 0, stream>>>(clean, patch, keys, clsArr);
  k_histsel<<<NT, 1024, 0, stream>>>(keys, thr, cnt);
  k_compact<<<dim3((NA + 255) / 256, NT), 256, 0, stream>>>(keys, thr, cnt, cand);
  k_sort   <<<NT, 1024, 0, stream>>>(clean, patch, cnt, cand, clsArr, boxesK, clsK, validK);
  k_ioumat <<<dim3(IOB, NT), 256, 0, stream>>>(boxesK, clsK, sup, diag);
  k_greedy <<<NT, 64, 0, stream>>>(sup, diag, validK, keepw);
  k_loss   <<<dim3(8, NB), 1024, 0, stream>>>(boxesK, clsK, keepw, part);
  k_final  <<<1, 64, 0, stream>>>(part, out);
}

// Round 7
// 275.033 us; speedup vs baseline: 2.2994x; 1.0107x over previous
//
#include <hip/hip_runtime.h>

// Pipeline (6 launches): k_score (async LDS staging) -> k_topsel (hist+select+compact+sort+gather)
//                        -> k_ioumat(+diag, triangular) -> k_greedy -> k_loss -> k_final

static constexpr int NB   = 8;
static constexpr int NA   = 25200;
static constexpr int NCLS = 80;
static constexpr int CH   = 85;
static constexpr int NT   = 16;    // 8 clean + 8 patch tasks
static constexpr int KMAX = 1024;
static constexpr int NBIN = 32768; // 15-bit prefix bins
static constexpr int PSH  = 17;    // key >> PSH = bin
static constexpr int CAP  = 2048;  // candidate buffer (hi[0,1024) eq[1024,2048))
static constexpr int IOB  = 34;    // x-blocks for k_ioumat (patch: 136 pairs*64 rows = 34*256)

// workspace byte offsets (all 16B aligned)
static constexpr size_t OFF_KEYS = 0;                                     // 1,612,800
static constexpr size_t OFF_CLS  = OFF_KEYS + (size_t)NT * NA * 4;        // 1,612,800
static constexpr size_t OFF_BOX  = OFF_CLS  + (size_t)NT * NA * 4;        // 262,144
static constexpr size_t OFF_CLSK = OFF_BOX  + (size_t)NT * KMAX * 16;     // 65,536
static constexpr size_t OFF_VALK = OFF_CLSK + (size_t)NT * KMAX * 4;      // 65,536
static constexpr size_t OFF_KEEP = OFF_VALK + (size_t)NT * KMAX * 4;      // 2,048
static constexpr size_t OFF_SUP  = OFF_KEEP + (size_t)NT * 16 * 8;        // 2,097,152
static constexpr size_t OFF_DIAG = OFF_SUP  + (size_t)NT * KMAX * 16 * 8; // 131,072
static constexpr size_t OFF_PART = OFF_DIAG + (size_t)NT * KMAX * 8;      // 512
// total ~5.85 MB

__device__ __forceinline__ unsigned okey(float f) {
  unsigned u = __float_as_uint(f);
  return (u & 0x80000000u) ? ~u : (u | 0x80000000u);
}

// ---------------- K1: per-anchor score/class — async global->LDS staging ----------------
__global__ __launch_bounds__(256) void k_score(const float* __restrict__ clean,
                                               const float* __restrict__ patch,
                                               unsigned* __restrict__ keys,
                                               int* __restrict__ clsArr) {
#pragma clang fp contract(off)
  const int t  = blockIdx.y;
  const int a0 = blockIdx.x * 64;
  const int nA = (NA - a0 < 64) ? (NA - a0) : 64;
  const float conf_th = (t < 8) ? 0.25f : 0.001f;
  const float* __restrict__ src = ((t < 8) ? clean : patch) + (size_t)(t & 7) * NA * CH;
  __shared__ float rows[64 * CH];   // 21,760 B, contiguous in exact lane order (no padding)
  const float4* g4 = (const float4*)(src + (size_t)a0 * CH);
  float4* rows4 = (float4*)rows;
  const int n4 = (nA * CH) >> 2;    // nA multiple of 16 -> nA*85 % 4 == 0
  const int wave = threadIdx.x >> 6;
  const int lane = threadIdx.x & 63;
  const int nchunk = (n4 + 63) >> 6;
  for (int c = wave; c < nchunk; c += 4) {
    const int i = (c << 6) + lane;  // float4 index; lds dst = uniform base + lane*16
    if (i < n4) {
      __builtin_amdgcn_global_load_lds(
          (const __attribute__((address_space(1))) void*)(g4 + i),
          (__attribute__((address_space(3))) void*)(rows4 + (c << 6)),
          16, 0, 0);
    }
  }
  __syncthreads();  // drains vmcnt before LDS reads

  const int ar = threadIdx.x >> 2;
  const int q  = threadIdx.x & 3;
  if (ar < nA) {
    const float* r = rows + ar * CH;
    const float obj = r[4];
    const int c0 = q * 20;
    float best = r[5 + c0] * obj;  // products first (matches ref argmax over cls_conf)
    int bc = c0;
    for (int c = c0 + 1; c < c0 + 20; ++c) {
      float v = r[5 + c] * obj;
      if (v > best) { best = v; bc = c; }
    }
    {
      float b2 = __shfl_down(best, 2); int c2 = __shfl_down(bc, 2);
      if (b2 > best || (b2 == best && c2 < bc)) { best = b2; bc = c2; }
      float b1 = __shfl_down(best, 1); int c1 = __shfl_down(bc, 1);
      if (b1 > best || (b1 == best && c1 < bc)) { best = b1; bc = c1; }
    }
    if (q == 0) {
      const bool valid = (obj > conf_th) && (best > conf_th);
      const float score = valid ? best : -1e30f;
      const int a = a0 + ar;
      keys[(size_t)t * NA + a]   = okey(score);
      clsArr[(size_t)t * NA + a] = bc;
    }
  }
}

// ---------------- K2: fused hist + select + compact(LDS) + bitonic + gather ----------------
__global__ __launch_bounds__(1024) void k_topsel(const unsigned* __restrict__ keys,
                                                 const int* __restrict__ clsArr,
                                                 const float* __restrict__ clean,
                                                 const float* __restrict__ patch,
                                                 float* __restrict__ boxesK,
                                                 int* __restrict__ clsK,
                                                 int* __restrict__ validK) {
#pragma clang fp contract(off)
  const int t = blockIdx.x;
  const unsigned K = (t < 8) ? 512u : 1024u;
  const float conf_th = (t < 8) ? 0.25f : 0.001f;
  __shared__ unsigned h32[NBIN / 2];        // 64 KB: two 16-bit bins per word
  __shared__ unsigned long long buf[CAP];   // 16 KB
  __shared__ unsigned scnt[2];
  __shared__ unsigned wtot[16], wsuf[16];
  __shared__ int s_chunk;
  __shared__ unsigned s_acc, s_B;
  const int tid = threadIdx.x;
  const int lane = tid & 63, wv = tid >> 6;
  for (int i = tid; i < NBIN / 2; i += 1024) h32[i] = 0u;
  for (int i = tid; i < CAP; i += 1024) buf[i] = 0ull;
  if (tid < 2) scnt[tid] = 0u;
  __syncthreads();
  const unsigned INVKEY = okey(-1e30f);
  const unsigned* kv = keys + (size_t)t * NA;
  // Phase A: histogram (uniform 25 iterations so ballots are full-wave)
  for (int i = tid; i < 25600; i += 1024) {
    const bool inb = (i < NA);
    unsigned key = inb ? kv[i] : 0u;
    const bool inv = inb && (key == INVKEY);
    unsigned long long mb = __ballot(inv);
    if (inb && !inv) {
      unsigned b = key >> PSH;
      atomicAdd(&h32[b >> 1], 1u << ((b & 1) * 16));
    } else if (inv && lane == (int)__ffsll(mb) - 1) {
      unsigned b = INVKEY >> PSH;
      atomicAdd(&h32[b >> 1], (unsigned)__popcll(mb) << ((b & 1) * 16));
    }
  }
  __syncthreads();
  // Phase B: chunk sums (32 bins/chunk) + hierarchical suffix scan (3 barriers)
  unsigned cnt_c = 0;
  for (int i = 0; i < 16; ++i) {
    unsigned v = h32[tid * 16 + i];
    cnt_c += (v & 0xFFFFu) + (v >> 16);
  }
  unsigned s = cnt_c;                       // wave-level inclusive suffix scan
  for (int off = 1; off < 64; off <<= 1) {
    unsigned v = __shfl_down(s, off);
    if (lane + off < 64) s += v;
  }
  if (lane == 0) wtot[wv] = s;
  __syncthreads();
  if (tid < 16) {
    unsigned acc = 0;
    for (int w2 = 15; w2 > tid; --w2) acc += wtot[w2];
    wsuf[tid] = acc;
  }
  __syncthreads();
  const unsigned suf = s + wsuf[wv];        // suffix over chunks [tid, 1023]
  if (suf >= K && suf - cnt_c < K) { s_chunk = tid; s_acc = suf - cnt_c; }
  __syncthreads();
  if (tid == 0) {
    unsigned acc = s_acc;
    unsigned res = (unsigned)(s_chunk * 32);
    for (int i = 31; i >= 0; --i) {
      int bb = s_chunk * 32 + i;
      unsigned v = h32[bb >> 1];
      unsigned c2 = (bb & 1) ? (v >> 16) : (v & 0xFFFFu);
      if (acc + c2 >= K) { res = (unsigned)bb; break; }
      acc += c2;
    }
    s_B = res;
  }
  __syncthreads();
  const unsigned B = s_B;
  // Phase C: compact into LDS buf (ballot-aggregated LDS counters)
  const unsigned long long lowmask =
      (lane == 0) ? 0ull : (0xFFFFFFFFFFFFFFFFull >> (64 - lane));
  for (int i = tid; i < 25600; i += 1024) {
    const bool inb = (i < NA);
    unsigned key = inb ? kv[i] : 0u;
    unsigned p = key >> PSH;
    const bool hi = inb && (p > B);
    const bool eq = inb && (p == B);
    const unsigned long long item =
        ((unsigned long long)key << 32) | (unsigned)(~(unsigned)i);
    unsigned long long mh = __ballot(hi);
    if (mh) {
      int leader = (int)__ffsll(mh) - 1;
      unsigned base2 = 0;
      if (lane == leader) base2 = atomicAdd(&scnt[0], (unsigned)__popcll(mh));
      base2 = __shfl(base2, leader);
      if (hi) {
        unsigned pos = base2 + (unsigned)__popcll(mh & lowmask);
        if (pos < 1024u) buf[pos] = item;   // hi count < K <= 1024 guaranteed
      }
    }
    unsigned long long me = __ballot(eq);
    if (me) {
      int leader = (int)__ffsll(me) - 1;
      unsigned base2 = 0;
      if (lane == leader) base2 = atomicAdd(&scnt[1], (unsigned)__popcll(me));
      base2 = __shfl(base2, leader);
      if (eq) {
        unsigned pos = base2 + (unsigned)__popcll(me & lowmask);
        if (pos < 1024u) buf[1024 + pos] = item;  // clamp safe: overflow only all-masked entries
      }
    }
  }
  __syncthreads();
  // Phase D: bitonic sort descending; equal keys -> larger ~idx (= smaller idx) first
  for (int kk2 = 2; kk2 <= CAP; kk2 <<= 1) {
    for (int j = kk2 >> 1; j > 0; j >>= 1) {
      for (int i = tid; i < CAP; i += 1024) {
        int ixj = i ^ j;
        if (ixj > i) {
          unsigned long long a = buf[i], b = buf[ixj];
          bool desc = ((i & kk2) == 0);
          if (desc ? (a < b) : (a > b)) { buf[i] = b; buf[ixj] = a; }
        }
      }
      __syncthreads();
    }
  }
  // Phase E: gather top-K boxes/cls
  const float* __restrict__ src = ((t < 8) ? clean : patch) + (size_t)(t & 7) * NA * CH;
  const unsigned vkey = okey(conf_th);
  for (int k = tid; k < (int)K; k += 1024) {
    unsigned long long v = buf[k];
    unsigned key = (unsigned)(v >> 32);
    int idx = (int)(~(unsigned)(v & 0xFFFFFFFFull));
    if (idx < 0 || idx >= NA) idx = 0;  // padding entries (key 0) masked downstream
    const float* r = src + (size_t)idx * CH;
    float cx = r[0], cy = r[1], w = r[2], h = r[3];
    float hw = w * 0.5f, hh = h * 0.5f;
    float* bo = boxesK + ((size_t)t * KMAX + k) * 4;
    bo[0] = cx - hw; bo[1] = cy - hh; bo[2] = cx + hw; bo[3] = cy + hh;
    clsK[t * KMAX + k]   = clsArr[(size_t)t * NA + idx];
    validK[t * KMAX + k] = (key > vkey) ? 1 : 0;
  }
}

// ---------------- K3: suppression bit-matrix, triangular enumeration ----------------
__global__ __launch_bounds__(256) void k_ioumat(const float* __restrict__ boxesK,
                                                const int* __restrict__ clsK,
                                                unsigned long long* __restrict__ sup,
                                                unsigned long long* __restrict__ diag) {
#pragma clang fp contract(off)
  const int t  = blockIdx.y;
  const int K  = (t < 8) ? 512 : 1024;
  const int lw = (t < 8) ? 3 : 4;
  const int nw = 1 << lw;
  const int npair = (nw * (nw + 1)) / 2;
  const int total = npair * 64;
  if (blockIdx.x * 256 >= total) return;
  __shared__ float X1[KMAX + 16], Y1[KMAX + 16], X2[KMAX + 16], Y2[KMAX + 16], AR[KMAX + 16];
  for (int i = threadIdx.x; i < K; i += 256) {
    const float* bo = boxesK + ((size_t)t * KMAX + i) * 4;
    float off = (float)clsK[t * KMAX + i] * 4096.0f;
    float x1 = bo[0] + off, y1 = bo[1] + off, x2 = bo[2] + off, y2 = bo[3] + off;
    const int ip = i + (i >> 6);
    X1[ip] = x1; Y1[ip] = y1; X2[ip] = x2; Y2[ip] = y2;
    AR[ip] = (x2 - x1) * (y2 - y1);
  }
  __syncthreads();
  unsigned long long* supt = sup + (size_t)t * (KMAX * 16);
  for (int widx = blockIdx.x * 256 + threadIdx.x; widx < total; widx += IOB * 256) {
    int p = widx >> 6;
    int row = widx & 63;
    int rb = 0, pr = p;
    while (pr >= nw - rb) { pr -= nw - rb; ++rb; }
    const int wc = rb + pr;
    const int i = rb * 64 + row;
    const int ipi = i + rb;
    const float x1i = X1[ipi], y1i = Y1[ipi], x2i = X2[ipi], y2i = Y2[ipi], ai = AR[ipi];
    unsigned long long m = 0ull;
    const int jb = (wc << 6) + wc;
    const bool offd = (wc > rb);
#pragma unroll 4
    for (int l = 0; l < 64; ++l) {
      const int jp = jb + l;                    // wave-uniform -> LDS broadcast
      float tlx = fmaxf(x1i, X1[jp]);
      float tly = fmaxf(y1i, Y1[jp]);
      float brx = fminf(x2i, X2[jp]);
      float bry = fminf(y2i, Y2[jp]);
      float w = fmaxf(brx - tlx, 0.0f);
      float h = fmaxf(bry - tly, 0.0f);
      float inter = w * h;
      float uni = (ai + AR[jp]) - inter;
      uni = (uni > 0.0f) ? uni : 1.0f;
      float iou = inter / uni;                  // IEEE div, bit-matches ref compare
      bool hit = (iou > 0.45f) && (offd || ((wc << 6) + l > i));
      m |= hit ? (1ull << l) : 0ull;
    }
    supt[(size_t)i * nw + wc] = m;
    if (wc == rb) diag[(size_t)t * KMAX + i] = m;
  }
}

// ---------------- K4: greedy NMS — LDS diag chain + sparse kept-row gather ----------------
__global__ __launch_bounds__(64) void k_greedy(const unsigned long long* __restrict__ sup,
                                               const unsigned long long* __restrict__ diag,
                                               const int* __restrict__ validK,
                                               unsigned long long* __restrict__ keepw) {
  const int t  = blockIdx.x;
  const int K  = (t < 8) ? 512 : 1024;
  const int lw = (t < 8) ? 3 : 4;
  const int nw = 1 << lw;
  const int lane = threadIdx.x;
  __shared__ unsigned long long sdiag[KMAX];
  const unsigned long long* dg = diag + (size_t)t * KMAX;
  for (int i = lane; i < K; i += 64) sdiag[i] = dg[i];
  int v16[16];
#pragma unroll
  for (int W = 0; W < 16; ++W)
    v16[W] = (W < nw) ? validK[t * KMAX + W * 64 + lane] : 0;
  unsigned long long vkeep = 0ull;
#pragma unroll
  for (int W = 0; W < 16; ++W)
    if (W < nw) {
      unsigned long long bl = __ballot(v16[W] != 0);
      if (lane == W) vkeep = bl;
    }
  __syncthreads();
  const int w = lane & (nw - 1);
  const int b = lane >> lw;
  const unsigned long long* base = sup + (size_t)t * (KMAX * 16);
  unsigned long long remv = 0ull;
  for (int W = 0; W < nw; ++W) {
    unsigned long long cur = __shfl(vkeep, W) & ~__shfl(remv, W);
    for (int rb = 0; rb < 64; rb += 16) {
      unsigned long long tm[16];
#pragma unroll
      for (int i2 = 0; i2 < 16; ++i2) tm[i2] = sdiag[W * 64 + rb + i2];
#pragma unroll
      for (int i2 = 0; i2 < 16; ++i2) {
        unsigned long long msk = 0ull - ((cur >> (rb + i2)) & 1ull);
        cur &= ~(tm[i2] & msk);
      }
    }
    if (lane == 0) keepw[t * 16 + W] = cur;
    if (W + 1 < nw) {
      const int r0 = b * nw;
      unsigned long long vv[16];
#pragma unroll
      for (int j = 0; j < 16; ++j) {
        bool take = (j < nw) && (w > W) && ((cur >> (r0 + j)) & 1ull);
        vv[j] = take ? base[(size_t)(W * 64 + r0 + j) * nw + w] : 0ull;
      }
      unsigned long long part = 0ull;
#pragma unroll
      for (int j = 0; j < 16; ++j) part |= vv[j];
      for (int s = nw; s < 64; s <<= 1) part |= __shfl_xor(part, s);
      remv |= part;
    }
  }
}

// ---------------- K5: masked-max IoU loss partials (1024 thr, 16 stripes) ----------------
__global__ __launch_bounds__(1024) void k_loss(const float* __restrict__ boxesK,
                                               const int* __restrict__ clsK,
                                               const unsigned long long* __restrict__ keepw,
                                               float* __restrict__ part) {
#pragma clang fp contract(off)
  const int img = blockIdx.y;
  const int chunk = blockIdx.x;
  const int tp = 8 + img;
  __shared__ float px1[KMAX], py1[KMAX], px2[KMAX], py2[KMAX], pa[KMAX];
  __shared__ int pcls[KMAX];
  __shared__ float red[1024];
  for (int j = threadIdx.x; j < KMAX; j += 1024) {
    const float* bo = boxesK + ((size_t)tp * KMAX + j) * 4;
    float x1 = bo[0] / 640.0f, y1 = bo[1] / 640.0f;
    float x2 = bo[2] / 640.0f, y2 = bo[3] / 640.0f;
    px1[j] = x1; py1[j] = y1; px2[j] = x2; py2[j] = y2;
    pa[j] = (x2 - x1) * (y2 - y1);
    int kept = (int)((keepw[tp * 16 + (j >> 6)] >> (j & 63)) & 1ull);
    pcls[j] = kept ? clsK[tp * KMAX + j] : -1;
  }
  __syncthreads();
  const int row = chunk * 64 + (threadIdx.x & 63);
  const int stripe = threadIdx.x >> 6;
  const int ck = (int)((keepw[img * 16 + (row >> 6)] >> (row & 63)) & 1ull);
  const float* bo = boxesK + ((size_t)img * KMAX + row) * 4;
  float cx1 = bo[0] / 640.0f, cy1 = bo[1] / 640.0f;
  float cx2 = bo[2] / 640.0f, cy2 = bo[3] / 640.0f;
  float ca = (cx2 - cx1) * (cy2 - cy1);
  const int ccls = clsK[img * KMAX + row];
  float m = 0.0f;
  if (ck) {
    const int j0 = stripe * 64;
    for (int j = j0; j < j0 + 64; ++j) {
      if (pcls[j] == ccls) {
        float tlx = fmaxf(cx1, px1[j]);
        float tly = fmaxf(cy1, py1[j]);
        float brx = fminf(cx2, px2[j]);
        float bry = fminf(cy2, py2[j]);
        float w = fmaxf(brx - tlx, 0.0f);
        float h = fmaxf(bry - tly, 0.0f);
        float inter = w * h;
        float uni = (ca + pa[j]) - inter;
        uni = (uni > 0.0f) ? uni : 1.0f;
        m = fmaxf(m, inter / uni);
      }
    }
  }
  red[threadIdx.x] = m;
  __syncthreads();
  if (threadIdx.x < 64) {
    float mm = red[threadIdx.x];
#pragma unroll
    for (int s = 1; s < 16; ++s) mm = fmaxf(mm, red[threadIdx.x + 64 * s]);
    float sv = ck ? mm : 0.0f;
    float nv = ck ? 1.0f : 0.0f;
    for (int off = 32; off > 0; off >>= 1) {
      sv += __shfl_down(sv, off);
      nv += __shfl_down(nv, off);
    }
    if (threadIdx.x == 0) {
      int b = img * 8 + chunk;
      part[b * 2 + 0] = sv;
      part[b * 2 + 1] = nv;
    }
  }
}

// ---------------- K6: deterministic final reduce ----------------
__global__ __launch_bounds__(64) void k_final(const float* __restrict__ part,
                                              float* __restrict__ out) {
  int lane = threadIdx.x;
  float sv = part[lane * 2 + 0];
  float nv = part[lane * 2 + 1];
  for (int off = 32; off > 0; off >>= 1) {
    sv += __shfl_down(sv, off);
    nv += __shfl_down(nv, off);
  }
  if (lane == 0) out[0] = (nv > 0.0f) ? (1.0f - sv / fmaxf(nv, 1.0f)) : 1.0f;
}

extern "C" void kernel_launch(void* const* d_in, const int* in_sizes, int n_in,
                              void* d_out, int out_size, void* d_ws, size_t ws_size,
                              hipStream_t stream) {
  const float* clean = (const float*)d_in[0];
  const float* patch = (const float*)d_in[1];
  char* ws = (char*)d_ws;
  unsigned* keys            = (unsigned*)(ws + OFF_KEYS);
  int* clsArr               = (int*)(ws + OFF_CLS);
  float* boxesK             = (float*)(ws + OFF_BOX);
  int* clsK                 = (int*)(ws + OFF_CLSK);
  int* validK               = (int*)(ws + OFF_VALK);
  unsigned long long* keepw = (unsigned long long*)(ws + OFF_KEEP);
  unsigned long long* sup   = (unsigned long long*)(ws + OFF_SUP);
  unsigned long long* diag  = (unsigned long long*)(ws + OFF_DIAG);
  float* part               = (float*)(ws + OFF_PART);
  float* out                = (float*)d_out;

  k_score  <<<dim3((NA + 63) / 64, NT), 256, 0, stream>>>(clean, patch, keys, clsArr);
  k_topsel <<<NT, 1024, 0, stream>>>(keys, clsArr, clean, patch, boxesK, clsK, validK);
  k_ioumat <<<dim3(IOB, NT), 256, 0, stream>>>(boxesK, clsK, sup, diag);
  k_greedy <<<NT, 64, 0, stream>>>(sup, diag, validK, keepw);
  k_loss   <<<dim3(8, NB), 1024, 0, stream>>>(boxesK, clsK, keepw, part);
  k_final  <<<1, 64, 0, stream>>>(part, out);
}